// Round 9
// baseline (290.919 us; speedup 1.0000x reference)
//
#include <hip/hip_runtime.h>
#include <math.h>

#define TOT_S   13294
#define NBATCH  2
#define CCH     512
#define MHEAD   8
#define PITCH   40   // LDS row pitch in bf16 elems (32 + 8 pad -> 80B)

typedef short     short8  __attribute__((ext_vector_type(8)));
typedef float     f32x4   __attribute__((ext_vector_type(4)));
typedef unsigned short u16x8 __attribute__((ext_vector_type(8)));
typedef unsigned short u16x4 __attribute__((ext_vector_type(4)));

__device__ __forceinline__ unsigned short f2bf(float f) {
    union { float f; unsigned int u; } v; v.f = f;
    unsigned int r = v.u + 0x7fffu + ((v.u >> 16) & 1u);   // RNE
    return (unsigned short)(r >> 16);
}
__device__ __forceinline__ float bf2f(unsigned short h) {
    union { unsigned int u; float f; } v; v.u = ((unsigned int)h) << 16;
    return v.f;
}

// ---------------------------------------------------------------------------
__global__ void cast_f32_bf16(const float* __restrict__ src,
                              unsigned short* __restrict__ dst, int n4)
{
    const int i = blockIdx.x * blockDim.x + threadIdx.x;
    if (i < n4) {
        const float4 v = *(const float4*)(src + (size_t)i * 4);
        u16x4 o;
        o[0] = f2bf(v.x); o[1] = f2bf(v.y); o[2] = f2bf(v.z); o[3] = f2bf(v.w);
        *(u16x4*)(dst + (size_t)i * 4) = o;
    }
}

// ---------------------------------------------------------------------------
// MFMA GEMM 1 v4: 128x128 tile, 8 waves, DOUBLE-BUFFERED single-barrier
// pipeline. Per iter: issue next-tile global loads -> ds_read+MFMA on
// buf[cur] (loads fly under compute) -> write buf[cur^1] -> ONE barrier.
// Fused f32->bf16 transpose staging of x.
// ---------------------------------------------------------------------------
__global__ __launch_bounds__(512)
void gemm_value_mfma(const unsigned short* __restrict__ Wb,
                     const float* __restrict__ x,
                     const float* __restrict__ bv,
                     const unsigned char* __restrict__ mask,
                     unsigned short* __restrict__ valb)
{
    __shared__ unsigned short Wl[2][128 * PITCH];   // 2 x 10 KB
    __shared__ unsigned short Al[2][128 * PITCH];   // 2 x 10 KB
    const int n  = blockIdx.z;
    const int ob = blockIdx.y * 128;
    const int sb = blockIdx.x * 128;
    const int tid = threadIdx.x;

    // ---- W staging: 128 rows x 32 k, one u16x8/thread
    const int r   = tid >> 2;          // 0..127
    const int seg = (tid & 3) * 8;     // 0,8,16,24
    const unsigned short* wsrc = Wb + ((size_t)(ob + r)) * CCH + seg;

    // ---- Act transposed staging: 32 c x 128 s f32, 4 float2/thread
    const int sp   = tid & 15;          // s-pair
    const int cgrp = (tid >> 4) & 15;   // k-pair id: k = 2*cgrp + cc
    const int half = tid >> 8;          // j = 2*half + jj
    const size_t XLIM = (size_t)NBATCH * CCH * TOT_S - 2;

    const int wave = tid >> 6, lane = tid & 63;
    const int m0 = (wave & 1) * 64, n0 = (wave >> 1) * 32;
    const int row16 = lane & 15, q = lane >> 4;

    // ---- prologue: tile 0 -> regs -> buf0
    u16x8 w0 = *(const u16x8*)(wsrc);
    float2 ax[2][2];
#pragma unroll
    for (int cc = 0; cc < 2; ++cc)
#pragma unroll
        for (int jj = 0; jj < 2; ++jj) {
            size_t off = ((size_t)n * CCH + 2 * cgrp + cc) * TOT_S
                       + sb + 2 * sp + 32 * (2 * half + jj);
            off = off > XLIM ? XLIM : off;
            ax[cc][jj] = *(const float2*)(x + off);
        }
    *(u16x8*)&Wl[0][r * PITCH + seg] = w0;
#pragma unroll
    for (int jj = 0; jj < 2; ++jj)
#pragma unroll
        for (int i = 0; i < 2; ++i) {
            const int s = 2 * sp + 32 * (2 * half + jj) + i;
            const float lo = i ? ax[0][jj].y : ax[0][jj].x;
            const float hi = i ? ax[1][jj].y : ax[1][jj].x;
            *(unsigned int*)&Al[0][(size_t)s * PITCH + 2 * cgrp] =
                (unsigned int)f2bf(lo) | ((unsigned int)f2bf(hi) << 16);
        }
    __syncthreads();

    f32x4 acc[4][2] = {};
    int cur = 0;
    for (int k0 = 0; k0 < CCH; k0 += 32) {
        const bool more = (k0 + 32) < CCH;
        // issue next-tile loads (fly under the MFMA phase)
        u16x8 wn = {};
        float2 axn[2][2];
        if (more) {
            wn = *(const u16x8*)(wsrc + k0 + 32);
#pragma unroll
            for (int cc = 0; cc < 2; ++cc)
#pragma unroll
                for (int jj = 0; jj < 2; ++jj) {
                    size_t off = ((size_t)n * CCH + k0 + 32 + 2 * cgrp + cc) * TOT_S
                               + sb + 2 * sp + 32 * (2 * half + jj);
                    off = off > XLIM ? XLIM : off;
                    axn[cc][jj] = *(const float2*)(x + off);
                }
        }
        // compute on buf[cur]
        short8 af[4], bfr[2];
#pragma unroll
        for (int mt = 0; mt < 4; ++mt)
            af[mt] = *(const short8*)&Wl[cur][(m0 + mt * 16 + row16) * PITCH + q * 8];
#pragma unroll
        for (int nt = 0; nt < 2; ++nt)
            bfr[nt] = *(const short8*)&Al[cur][(n0 + nt * 16 + row16) * PITCH + q * 8];
#pragma unroll
        for (int mt = 0; mt < 4; ++mt)
#pragma unroll
            for (int nt = 0; nt < 2; ++nt)
                acc[mt][nt] = __builtin_amdgcn_mfma_f32_16x16x32_bf16(
                    af[mt], bfr[nt], acc[mt][nt], 0, 0, 0);
        // write next tile into the other buffer
        if (more) {
            *(u16x8*)&Wl[cur ^ 1][r * PITCH + seg] = wn;
#pragma unroll
            for (int jj = 0; jj < 2; ++jj)
#pragma unroll
                for (int i = 0; i < 2; ++i) {
                    const int s = 2 * sp + 32 * (2 * half + jj) + i;
                    const float lo = i ? axn[0][jj].y : axn[0][jj].x;
                    const float hi = i ? axn[1][jj].y : axn[1][jj].x;
                    *(unsigned int*)&Al[cur ^ 1][(size_t)s * PITCH + 2 * cgrp] =
                        (unsigned int)f2bf(lo) | ((unsigned int)f2bf(hi) << 16);
                }
        }
        __syncthreads();
        cur ^= 1;
    }

#pragma unroll
    for (int nt = 0; nt < 2; ++nt) {
        const int s = sb + n0 + nt * 16 + row16;
        if (s >= TOT_S) continue;
        const float msk = mask[(size_t)n * TOT_S + s] ? 0.f : 1.f;
        unsigned short* orow = valb + ((size_t)n * TOT_S + s) * CCH + ob + m0;
#pragma unroll
        for (int mt = 0; mt < 4; ++mt) {
            const f32x4 bvv = *(const f32x4*)(bv + ob + m0 + mt * 16 + q * 4);
            const f32x4 a = acc[mt][nt];
            u16x4 ov;
            ov[0] = f2bf((a[0] + bvv[0]) * msk);
            ov[1] = f2bf((a[1] + bvv[1]) * msk);
            ov[2] = f2bf((a[2] + bvv[2]) * msk);
            ov[3] = f2bf((a[3] + bvv[3]) * msk);
            *(u16x4*)(orow + mt * 16 + q * 4) = ov;
        }
    }
}

// ---------------------------------------------------------------------------
// MFMA GEMM 2 (offsets+logits), fused transpose staging of (x+pos)*~mask.
// ---------------------------------------------------------------------------
__global__ __launch_bounds__(256)
void gemm_offw_mfma(const unsigned short* __restrict__ Wlb,
                    const unsigned short* __restrict__ Wwb,
                    const float* __restrict__ bloc, const float* __restrict__ bw,
                    const float* __restrict__ x, const float* __restrict__ pos,
                    const unsigned char* __restrict__ mask,
                    float* __restrict__ offw)
{
    __shared__ unsigned short Wl[128 * PITCH];
    __shared__ unsigned short Al[128 * PITCH];
    const int n  = blockIdx.z;
    const int sb = blockIdx.x * 128;
    const int tid = threadIdx.x;

    // ---- W staging (unchanged)
    const int r   = tid >> 1;
    const int seg = (tid & 1) * 16;
    const bool wzero = (r >= 96);
    const unsigned short* wsrc =
        (r < 64) ? (Wlb + (size_t)r * CCH + seg)
                 : (Wwb + (size_t)((r < 96 ? r : 95) - 64) * CCH + seg);
    unsigned short* wdst = &Wl[r * PITCH + seg];

    // ---- Act transposed-staging mapping
    const int sp   = tid & 15;
    const int cpid = tid >> 4;
    const size_t XLIM = (size_t)NBATCH * CCH * TOT_S - 2;
    float mkm[8];
#pragma unroll
    for (int j = 0; j < 4; ++j)
#pragma unroll
        for (int i = 0; i < 2; ++i) {
            const int s = sb + 2 * sp + 32 * j + i;
            const int sc = s < TOT_S ? s : TOT_S - 1;
            mkm[j * 2 + i] = mask[(size_t)n * TOT_S + sc] ? 0.f : 1.f;
        }

    const int wave = tid >> 6, lane = tid & 63;
    const int m0 = (wave & 1) * 64, n0 = (wave >> 1) * 64;
    const int row16 = lane & 15, q = lane >> 4;

    u16x8 w0 = {}, w1 = {};
    if (!wzero) { w0 = *(const u16x8*)(wsrc); w1 = *(const u16x8*)(wsrc + 8); }
    float2 ax[2][4], ap[2][4];
#pragma unroll
    for (int cc = 0; cc < 2; ++cc)
#pragma unroll
        for (int j = 0; j < 4; ++j) {
            size_t off = ((size_t)n * CCH + 2 * cpid + cc) * TOT_S
                       + sb + 2 * sp + 32 * j;
            off = off > XLIM ? XLIM : off;
            ax[cc][j] = *(const float2*)(x + off);
            ap[cc][j] = *(const float2*)(pos + off);
        }

    f32x4 acc[4][4] = {};
    for (int k0 = 0; k0 < CCH; k0 += 32) {
        *(u16x8*)wdst = w0; *(u16x8*)(wdst + 8) = w1;
#pragma unroll
        for (int j = 0; j < 4; ++j)
#pragma unroll
            for (int i = 0; i < 2; ++i) {
                const int s = 2 * sp + 32 * j + i;
                const float lo = (i ? ax[0][j].y + ap[0][j].y
                                    : ax[0][j].x + ap[0][j].x) * mkm[j * 2 + i];
                const float hi = (i ? ax[1][j].y + ap[1][j].y
                                    : ax[1][j].x + ap[1][j].x) * mkm[j * 2 + i];
                const unsigned int pk =
                    (unsigned int)f2bf(lo) | ((unsigned int)f2bf(hi) << 16);
                *(unsigned int*)&Al[(size_t)s * PITCH + 2 * cpid] = pk;
            }
        __syncthreads();
        if (k0 + 32 < CCH) {
            if (!wzero) {
                w0 = *(const u16x8*)(wsrc + k0 + 32);
                w1 = *(const u16x8*)(wsrc + k0 + 40);
            }
#pragma unroll
            for (int cc = 0; cc < 2; ++cc)
#pragma unroll
                for (int j = 0; j < 4; ++j) {
                    size_t off = ((size_t)n * CCH + k0 + 32 + 2 * cpid + cc) * TOT_S
                               + sb + 2 * sp + 32 * j;
                    off = off > XLIM ? XLIM : off;
                    ax[cc][j] = *(const float2*)(x + off);
                    ap[cc][j] = *(const float2*)(pos + off);
                }
        }
        short8 af[4], bfr[4];
#pragma unroll
        for (int mt = 0; mt < 4; ++mt)
            af[mt] = *(const short8*)&Wl[(m0 + mt * 16 + row16) * PITCH + q * 8];
#pragma unroll
        for (int nt = 0; nt < 4; ++nt)
            bfr[nt] = *(const short8*)&Al[(n0 + nt * 16 + row16) * PITCH + q * 8];
#pragma unroll
        for (int mt = 0; mt < 4; ++mt)
#pragma unroll
            for (int nt = 0; nt < 4; ++nt)
                acc[mt][nt] = __builtin_amdgcn_mfma_f32_16x16x32_bf16(
                    af[mt], bfr[nt], acc[mt][nt], 0, 0, 0);
        __syncthreads();
    }

#pragma unroll
    for (int nt = 0; nt < 4; ++nt) {
        const int s = sb + n0 + nt * 16 + row16;
        if (s >= TOT_S) continue;
        float* orow = offw + ((size_t)n * TOT_S + s) * 96;
#pragma unroll
        for (int mt = 0; mt < 4; ++mt) {
            const int o = m0 + mt * 16 + q * 4;
            if (o < 96) {
                const float* bsrc = (o < 64) ? (bloc + o) : (bw + o - 64);
                const f32x4 bb = *(const f32x4*)bsrc;
                f32x4 v = acc[mt][nt];
                v[0] += bb[0]; v[1] += bb[1]; v[2] += bb[2]; v[3] += bb[3];
                *(f32x4*)(orow + o) = v;
            }
        }
    }
}

// ---------------------------------------------------------------------------
// Sampling v2: ONE WAVE PER (n,s). lane -> head m = lane>>3, channels
// c = m*64 + (lane&7)*8 .. +8  (== lane*8: output row is one contiguous 1KiB
// store). 16B/lane gathers; branchless clamp + masked corner weights.
// ---------------------------------------------------------------------------
__global__ __launch_bounds__(256)
void sample_attn(const unsigned short* __restrict__ value,  // (N,S,512) bf16
                 const float* __restrict__ offw,            // (N,S,96)
                 const float* __restrict__ vsizes,
                 const float* __restrict__ vscales,
                 unsigned short* __restrict__ samp)         // (N,S,512) bf16
{
    const int lane = threadIdx.x;
    const int item = blockIdx.x * blockDim.y + threadIdx.y;
    const int total = NBATCH * TOT_S;
    if (item >= total) return;
    const int s = item % TOT_S;
    const int n = item / TOT_S;
    const int m = lane >> 3;

    // query level + pixel-center coords (wave-uniform)
    int lvl; float prex, prey;
    if (s < 10000)      { lvl = 0; const int l = s;         const int qq = l / 100; prey = qq + 0.5f; prex = (l - qq * 100) + 0.5f; }
    else if (s < 12500) { lvl = 1; const int l = s - 10000; const int qq = l / 50;  prey = qq + 0.5f; prex = (l - qq * 50)  + 0.5f; }
    else if (s < 13125) { lvl = 2; const int l = s - 12500; const int qq = l / 25;  prey = qq + 0.5f; prex = (l - qq * 25)  + 0.5f; }
    else                { lvl = 3; const int l = s - 13125; const int qq = l / 13;  prey = qq + 0.5f; prex = (l - qq * 13)  + 0.5f; }

    const float* ow = offw + ((size_t)n * TOT_S + s) * 96;

    // per-head softmax over 4 logits (replicated across the 8 lanes of a head)
    const float w0 = ow[64 + m * 4 + 0], w1 = ow[64 + m * 4 + 1];
    const float w2 = ow[64 + m * 4 + 2], w3 = ow[64 + m * 4 + 3];
    const float mx = fmaxf(fmaxf(w0, w1), fmaxf(w2, w3));
    const float e0 = expf(w0 - mx), e1 = expf(w1 - mx), e2 = expf(w2 - mx), e3 = expf(w3 - mx);
    const float inv = 1.f / (e0 + e1 + e2 + e3);
    const float wgt[4] = { e0 * inv, e1 * inv, e2 * inv, e3 * inv };

    const int HS[4]  = { 100, 50, 25, 13 };
    const int WS[4]  = { 100, 50, 25, 13 };
    const int CUR[4] = { 0, 10000, 12500, 13125 };

    const float invsx = 1.f / vsizes[((n * 4) + lvl) * 2 + 0];
    const float invsy = 1.f / vsizes[((n * 4) + lvl) * 2 + 1];
    // channel base: c = lane*8
    const unsigned short* vbase = value + (size_t)n * TOT_S * CCH + lane * 8;

    float acc[8] = {};
#pragma unroll
    for (int f = 0; f < 4; ++f) {
        const float offx = ow[(m * 4 + f) * 2 + 0];
        const float offy = ow[(m * 4 + f) * 2 + 1];
        const float scx = 2.f * vscales[((n * 4) + f) * 2 + 0] * invsx;
        const float scy = 2.f * vscales[((n * 4) + f) * 2 + 1] * invsy;
        const int Wf = WS[f], Hf = HS[f], cf = CUR[f];
        const float xi = (offx + prex) * scx * (Wf * 0.5f) - 0.5f;
        const float yi = (offy + prey) * scy * (Hf * 0.5f) - 0.5f;
        const float x0f = floorf(xi), y0f = floorf(yi);
        const float wx1 = xi - x0f, wy1 = yi - y0f;
        const float wx0 = 1.f - wx1, wy0 = 1.f - wy1;
        const int x0 = (int)x0f, y0 = (int)y0f;
        const bool xin0 = (x0 >= 0) && (x0 < Wf);
        const bool xin1 = (x0 + 1 >= 0) && (x0 + 1 < Wf);
        const bool yin0 = (y0 >= 0) && (y0 < Hf);
        const bool yin1 = (y0 + 1 >= 0) && (y0 + 1 < Hf);
        // masked corner weights (fold level weight in), clamped indices
        const float cw00 = (xin0 && yin0) ? wgt[f] * wx0 * wy0 : 0.f;
        const float cw10 = (xin1 && yin0) ? wgt[f] * wx1 * wy0 : 0.f;
        const float cw01 = (xin0 && yin1) ? wgt[f] * wx0 * wy1 : 0.f;
        const float cw11 = (xin1 && yin1) ? wgt[f] * wx1 * wy1 : 0.f;
        const int x0c = min(max(x0, 0), Wf - 1);
        const int x1c = min(max(x0 + 1, 0), Wf - 1);
        const int y0c = min(max(y0, 0), Hf - 1);
        const int y1c = min(max(y0 + 1, 0), Hf - 1);
        const unsigned short* row0 = vbase + (size_t)(cf + y0c * Wf) * CCH;
        const unsigned short* row1 = vbase + (size_t)(cf + y1c * Wf) * CCH;
        const u16x8 v00 = *(const u16x8*)(row0 + (size_t)x0c * CCH);
        const u16x8 v10 = *(const u16x8*)(row0 + (size_t)x1c * CCH);
        const u16x8 v01 = *(const u16x8*)(row1 + (size_t)x0c * CCH);
        const u16x8 v11 = *(const u16x8*)(row1 + (size_t)x1c * CCH);
#pragma unroll
        for (int j = 0; j < 8; ++j) {
            acc[j] += cw00 * bf2f(v00[j]) + cw10 * bf2f(v10[j])
                    + cw01 * bf2f(v01[j]) + cw11 * bf2f(v11[j]);
        }
    }

    u16x8 ov;
#pragma unroll
    for (int j = 0; j < 8; ++j) ov[j] = f2bf(acc[j]);
    *(u16x8*)(samp + ((size_t)n * TOT_S + s) * CCH + lane * 8) = ov;
}

// ---------------------------------------------------------------------------
// MFMA GEMM 3 v4: 128x128, 8 waves, double-buffered single-barrier pipeline.
// out[n][o][s] = (sum_c Wo[o][c]*samp[s][c] + bo[o]) * scale[o]
// ---------------------------------------------------------------------------
__global__ __launch_bounds__(512)
void gemm_out_mfma(const unsigned short* __restrict__ Wob,
                   const unsigned short* __restrict__ Sampb,
                   const float* __restrict__ bo, const float* __restrict__ scale,
                   float* __restrict__ out)
{
    __shared__ unsigned short Sl[2][128 * PITCH];
    __shared__ unsigned short Wl[2][128 * PITCH];
    const int n  = blockIdx.z;
    const int ob = blockIdx.y * 128;
    const int sb = blockIdx.x * 128;
    const int tid = threadIdx.x;
    const int r   = tid >> 2;          // 0..127
    const int seg = (tid & 3) * 8;     // 0,8,16,24
    const int sr = min(sb + r, TOT_S - 1);
    const unsigned short* ssrc = Sampb + ((size_t)n * TOT_S + sr) * CCH + seg;
    const unsigned short* wsrc = Wob + ((size_t)(ob + r)) * CCH + seg;

    const int wave = tid >> 6, lane = tid & 63;
    const int m0 = (wave & 1) * 64, n0 = (wave >> 1) * 32;
    const int row16 = lane & 15, q = lane >> 4;

    // prologue: tile 0
    u16x8 s0v = *(const u16x8*)(ssrc);
    u16x8 w0v = *(const u16x8*)(wsrc);
    *(u16x8*)&Sl[0][r * PITCH + seg] = s0v;
    *(u16x8*)&Wl[0][r * PITCH + seg] = w0v;
    __syncthreads();

    f32x4 acc[4][2] = {};
    int cur = 0;
    for (int k0 = 0; k0 < CCH; k0 += 32) {
        const bool more = (k0 + 32) < CCH;
        u16x8 sn = {}, wn = {};
        if (more) {
            sn = *(const u16x8*)(ssrc + k0 + 32);
            wn = *(const u16x8*)(wsrc + k0 + 32);
        }
        short8 af[4], bfr[2];
#pragma unroll
        for (int mt = 0; mt < 4; ++mt)
            af[mt] = *(const short8*)&Sl[cur][(m0 + mt * 16 + row16) * PITCH + q * 8];
#pragma unroll
        for (int nt = 0; nt < 2; ++nt)
            bfr[nt] = *(const short8*)&Wl[cur][(n0 + nt * 16 + row16) * PITCH + q * 8];
#pragma unroll
        for (int mt = 0; mt < 4; ++mt)
#pragma unroll
            for (int nt = 0; nt < 2; ++nt)
                acc[mt][nt] = __builtin_amdgcn_mfma_f32_16x16x32_bf16(
                    af[mt], bfr[nt], acc[mt][nt], 0, 0, 0);
        if (more) {
            *(u16x8*)&Sl[cur ^ 1][r * PITCH + seg] = sn;
            *(u16x8*)&Wl[cur ^ 1][r * PITCH + seg] = wn;
        }
        __syncthreads();
        cur ^= 1;
    }

#pragma unroll
    for (int nt = 0; nt < 2; ++nt) {
        const int o = ob + n0 + nt * 16 + row16;
        const float bo_ = bo[o];
        const float sc_ = scale[o];
        float* orow = out + ((size_t)n * CCH + o) * (size_t)TOT_S;
#pragma unroll
        for (int mt = 0; mt < 4; ++mt) {
            const int s0 = sb + m0 + mt * 16 + q * 4;
            const f32x4 a = acc[mt][nt];
            if (s0 + 3 < TOT_S) {
                float2 v0 = make_float2((a[0] + bo_) * sc_, (a[1] + bo_) * sc_);
                float2 v1 = make_float2((a[2] + bo_) * sc_, (a[3] + bo_) * sc_);
                *(float2*)(orow + s0) = v0;
                *(float2*)(orow + s0 + 2) = v1;
            } else {
                for (int i = 0; i < 4; ++i)
                    if (s0 + i < TOT_S) orow[s0 + i] = (a[i] + bo_) * sc_;
            }
        }
    }
}

// ---------------------------------------------------------------------------
extern "C" void kernel_launch(void* const* d_in, const int* in_sizes, int n_in,
                              void* d_out, int out_size, void* d_ws, size_t ws_size,
                              hipStream_t stream)
{
    const float* x     = (const float*)d_in[0];
    const float* pos   = (const float*)d_in[1];
    const unsigned char* mask = (const unsigned char*)d_in[2];
    const float* vsz   = (const float*)d_in[3];
    const float* vsc   = (const float*)d_in[4];
    const float* Wv    = (const float*)d_in[5];
    const float* bv    = (const float*)d_in[6];
    const float* Wloc  = (const float*)d_in[7];
    const float* bloc  = (const float*)d_in[8];
    const float* Ww    = (const float*)d_in[9];
    const float* bw    = (const float*)d_in[10];
    const float* Wo    = (const float*)d_in[11];
    const float* bo    = (const float*)d_in[12];
    const float* scale = (const float*)d_in[13];
    float* out = (float*)d_out;

    const size_t SC = (size_t)TOT_S * CCH;
    unsigned short* valb  = (unsigned short*)d_ws;
    unsigned short* sampb = valb  + 2 * SC;
    float* offw = (float*)(sampb + 2 * SC);
    unsigned short* wvb = (unsigned short*)(offw + 2 * (size_t)TOT_S * 96);
    unsigned short* wob = wvb + 512 * 512;
    unsigned short* wlb = wob + 512 * 512;
    unsigned short* wwb = wlb + 64 * 512;

    cast_f32_bf16<<<256, 256, 0, stream>>>(Wv,   wvb, 512 * 512 / 4);
    cast_f32_bf16<<<256, 256, 0, stream>>>(Wo,   wob, 512 * 512 / 4);
    cast_f32_bf16<<<32,  256, 0, stream>>>(Wloc, wlb, 64 * 512 / 4);
    cast_f32_bf16<<<16,  256, 0, stream>>>(Ww,   wwb, 32 * 512 / 4);

    const int sTiles = (TOT_S + 127) / 128;  // 104

    gemm_value_mfma<<<dim3(sTiles, CCH / 128, NBATCH), 512, 0, stream>>>(
        wvb, x, bv, mask, valb);
    gemm_offw_mfma<<<dim3(sTiles, 1, NBATCH), 256, 0, stream>>>(
        wlb, wwb, bloc, bw, x, pos, mask, offw);

    const int items = NBATCH * TOT_S;   // one wave per (n,s)
    sample_attn<<<(items + 3) / 4, dim3(64, 4), 0, stream>>>(valb, offw, vsz, vsc, sampb);

    gemm_out_mfma<<<dim3(sTiles, CCH / 128, NBATCH), 512, 0, stream>>>(
        wob, sampb, bo, scale, out);
}

// Round 11
// 287.691 us; speedup vs baseline: 1.0112x; 1.0112x over previous
//
#include <hip/hip_runtime.h>
#include <math.h>

#define TOT_S   13294
#define NBATCH  2
#define CCH     512
#define MHEAD   8
#define PITCH   40   // LDS row pitch in bf16 elems (32 + 8 pad -> 80B)

typedef short     short8  __attribute__((ext_vector_type(8)));
typedef float     f32x4   __attribute__((ext_vector_type(4)));
typedef unsigned short u16x8 __attribute__((ext_vector_type(8)));
typedef unsigned short u16x4 __attribute__((ext_vector_type(4)));

__device__ __forceinline__ unsigned short f2bf(float f) {
    union { float f; unsigned int u; } v; v.f = f;
    unsigned int r = v.u + 0x7fffu + ((v.u >> 16) & 1u);   // RNE
    return (unsigned short)(r >> 16);
}
__device__ __forceinline__ float bf2f(unsigned short h) {
    union { unsigned int u; float f; } v; v.u = ((unsigned int)h) << 16;
    return v.f;
}

// ---------------------------------------------------------------------------
__global__ void cast_f32_bf16(const float* __restrict__ src,
                              unsigned short* __restrict__ dst, int n4)
{
    const int i = blockIdx.x * blockDim.x + threadIdx.x;
    if (i < n4) {
        const float4 v = *(const float4*)(src + (size_t)i * 4);
        u16x4 o;
        o[0] = f2bf(v.x); o[1] = f2bf(v.y); o[2] = f2bf(v.z); o[3] = f2bf(v.w);
        *(u16x4*)(dst + (size_t)i * 4) = o;
    }
}

// ---------------------------------------------------------------------------
// MFMA GEMM 1 v5: 128x128 tile, 8 waves, BK=64 via TWO 32-wide LDS arrays
// (same bank geometry as BK=32; no new conflicts). 8 K-iterations instead of
// 16 -> halves the per-iteration fixed cost count. Fused f32->bf16 transpose
// staging of x.
// ---------------------------------------------------------------------------
__global__ __launch_bounds__(512)
void gemm_value_mfma(const unsigned short* __restrict__ Wb,
                     const float* __restrict__ x,
                     const float* __restrict__ bv,
                     const unsigned char* __restrict__ mask,
                     unsigned short* __restrict__ valb)
{
    __shared__ unsigned short Wl[2][128 * PITCH];   // k-halves, 2 x 10 KB
    __shared__ unsigned short Al[2][128 * PITCH];
    const int n  = blockIdx.z;
    const int ob = blockIdx.y * 128;
    const int sb = blockIdx.x * 128;
    const int tid = threadIdx.x;

    // ---- W staging: 128 rows x 64 k; slot = tid&3 -> {h, segh}
    const int r    = tid >> 2;              // 0..127
    const int wh   = (tid & 3) >> 1;        // k-half 0/1
    const int segh = (tid & 1) * 16;        // 0 or 16 within half
    const unsigned short* wsrc = Wb + ((size_t)(ob + r)) * CCH + wh * 32 + segh;
    unsigned short* wdst = &Wl[wh][r * PITCH + segh];

    // ---- Act transposed staging: 64 c x 128 s f32 per iter
    const int sp   = tid & 15;          // s-pair
    const int cgrp = (tid >> 4) & 15;   // k-pair within half: k = 2*cgrp + cc
    const int half = tid >> 8;          // j = 2*half + jj
    const size_t XLIM = (size_t)NBATCH * CCH * TOT_S - 2;

    const int wave = tid >> 6, lane = tid & 63;
    const int m0 = (wave & 1) * 64, n0 = (wave >> 1) * 32;
    const int row16 = lane & 15, q = lane >> 4;

    // ---- prologue: load tile 0
    u16x8 w0 = *(const u16x8*)(wsrc);
    u16x8 w1 = *(const u16x8*)(wsrc + 8);
    float2 ax[2][2][2];   // [kh][cc][jj]
#pragma unroll
    for (int kh = 0; kh < 2; ++kh)
#pragma unroll
        for (int cc = 0; cc < 2; ++cc)
#pragma unroll
            for (int jj = 0; jj < 2; ++jj) {
                size_t off = ((size_t)n * CCH + kh * 32 + 2 * cgrp + cc) * TOT_S
                           + sb + 2 * sp + 32 * (2 * half + jj);
                off = off > XLIM ? XLIM : off;
                ax[kh][cc][jj] = *(const float2*)(x + off);
            }

    f32x4 acc[4][2] = {};
    for (int k0 = 0; k0 < CCH; k0 += 64) {
        // write tile k0 to LDS
        *(u16x8*)wdst = w0; *(u16x8*)(wdst + 8) = w1;
#pragma unroll
        for (int kh = 0; kh < 2; ++kh)
#pragma unroll
            for (int jj = 0; jj < 2; ++jj)
#pragma unroll
                for (int i = 0; i < 2; ++i) {
                    const int s = 2 * sp + 32 * (2 * half + jj) + i;
                    const float lo = i ? ax[kh][0][jj].y : ax[kh][0][jj].x;
                    const float hi = i ? ax[kh][1][jj].y : ax[kh][1][jj].x;
                    *(unsigned int*)&Al[kh][(size_t)s * PITCH + 2 * cgrp] =
                        (unsigned int)f2bf(lo) | ((unsigned int)f2bf(hi) << 16);
                }
        __syncthreads();
        // prefetch tile k0+64
        if (k0 + 64 < CCH) {
            w0 = *(const u16x8*)(wsrc + k0 + 64);
            w1 = *(const u16x8*)(wsrc + k0 + 72);
#pragma unroll
            for (int kh = 0; kh < 2; ++kh)
#pragma unroll
                for (int cc = 0; cc < 2; ++cc)
#pragma unroll
                    for (int jj = 0; jj < 2; ++jj) {
                        size_t off = ((size_t)n * CCH + k0 + 64 + kh * 32
                                      + 2 * cgrp + cc) * TOT_S
                                   + sb + 2 * sp + 32 * (2 * half + jj);
                        off = off > XLIM ? XLIM : off;
                        ax[kh][cc][jj] = *(const float2*)(x + off);
                    }
        }
        // compute both k-halves
#pragma unroll
        for (int kh = 0; kh < 2; ++kh) {
            short8 af[4], bfr[2];
#pragma unroll
            for (int mt = 0; mt < 4; ++mt)
                af[mt] = *(const short8*)&Wl[kh][(m0 + mt * 16 + row16) * PITCH + q * 8];
#pragma unroll
            for (int nt = 0; nt < 2; ++nt)
                bfr[nt] = *(const short8*)&Al[kh][(n0 + nt * 16 + row16) * PITCH + q * 8];
#pragma unroll
            for (int mt = 0; mt < 4; ++mt)
#pragma unroll
                for (int nt = 0; nt < 2; ++nt)
                    acc[mt][nt] = __builtin_amdgcn_mfma_f32_16x16x32_bf16(
                        af[mt], bfr[nt], acc[mt][nt], 0, 0, 0);
        }
        __syncthreads();
    }

#pragma unroll
    for (int nt = 0; nt < 2; ++nt) {
        const int s = sb + n0 + nt * 16 + row16;
        if (s >= TOT_S) continue;
        const float msk = mask[(size_t)n * TOT_S + s] ? 0.f : 1.f;
        unsigned short* orow = valb + ((size_t)n * TOT_S + s) * CCH + ob + m0;
#pragma unroll
        for (int mt = 0; mt < 4; ++mt) {
            const f32x4 bvv = *(const f32x4*)(bv + ob + m0 + mt * 16 + q * 4);
            const f32x4 a = acc[mt][nt];
            u16x4 ov;
            ov[0] = f2bf((a[0] + bvv[0]) * msk);
            ov[1] = f2bf((a[1] + bvv[1]) * msk);
            ov[2] = f2bf((a[2] + bvv[2]) * msk);
            ov[3] = f2bf((a[3] + bvv[3]) * msk);
            *(u16x4*)(orow + mt * 16 + q * 4) = ov;
        }
    }
}

// ---------------------------------------------------------------------------
// MFMA GEMM 2 (offsets+logits), fused transpose staging of (x+pos)*~mask.
// ---------------------------------------------------------------------------
__global__ __launch_bounds__(256)
void gemm_offw_mfma(const unsigned short* __restrict__ Wlb,
                    const unsigned short* __restrict__ Wwb,
                    const float* __restrict__ bloc, const float* __restrict__ bw,
                    const float* __restrict__ x, const float* __restrict__ pos,
                    const unsigned char* __restrict__ mask,
                    float* __restrict__ offw)
{
    __shared__ unsigned short Wl[128 * PITCH];
    __shared__ unsigned short Al[128 * PITCH];
    const int n  = blockIdx.z;
    const int sb = blockIdx.x * 128;
    const int tid = threadIdx.x;

    // ---- W staging (unchanged)
    const int r   = tid >> 1;
    const int seg = (tid & 1) * 16;
    const bool wzero = (r >= 96);
    const unsigned short* wsrc =
        (r < 64) ? (Wlb + (size_t)r * CCH + seg)
                 : (Wwb + (size_t)((r < 96 ? r : 95) - 64) * CCH + seg);
    unsigned short* wdst = &Wl[r * PITCH + seg];

    // ---- Act transposed-staging mapping
    const int sp   = tid & 15;
    const int cpid = tid >> 4;
    const size_t XLIM = (size_t)NBATCH * CCH * TOT_S - 2;
    float mkm[8];
#pragma unroll
    for (int j = 0; j < 4; ++j)
#pragma unroll
        for (int i = 0; i < 2; ++i) {
            const int s = sb + 2 * sp + 32 * j + i;
            const int sc = s < TOT_S ? s : TOT_S - 1;
            mkm[j * 2 + i] = mask[(size_t)n * TOT_S + sc] ? 0.f : 1.f;
        }

    const int wave = tid >> 6, lane = tid & 63;
    const int m0 = (wave & 1) * 64, n0 = (wave >> 1) * 64;
    const int row16 = lane & 15, q = lane >> 4;

    u16x8 w0 = {}, w1 = {};
    if (!wzero) { w0 = *(const u16x8*)(wsrc); w1 = *(const u16x8*)(wsrc + 8); }
    float2 ax[2][4], ap[2][4];
#pragma unroll
    for (int cc = 0; cc < 2; ++cc)
#pragma unroll
        for (int j = 0; j < 4; ++j) {
            size_t off = ((size_t)n * CCH + 2 * cpid + cc) * TOT_S
                       + sb + 2 * sp + 32 * j;
            off = off > XLIM ? XLIM : off;
            ax[cc][j] = *(const float2*)(x + off);
            ap[cc][j] = *(const float2*)(pos + off);
        }

    f32x4 acc[4][4] = {};
    for (int k0 = 0; k0 < CCH; k0 += 32) {
        *(u16x8*)wdst = w0; *(u16x8*)(wdst + 8) = w1;
#pragma unroll
        for (int j = 0; j < 4; ++j)
#pragma unroll
            for (int i = 0; i < 2; ++i) {
                const int s = 2 * sp + 32 * j + i;
                const float lo = (i ? ax[0][j].y + ap[0][j].y
                                    : ax[0][j].x + ap[0][j].x) * mkm[j * 2 + i];
                const float hi = (i ? ax[1][j].y + ap[1][j].y
                                    : ax[1][j].x + ap[1][j].x) * mkm[j * 2 + i];
                const unsigned int pk =
                    (unsigned int)f2bf(lo) | ((unsigned int)f2bf(hi) << 16);
                *(unsigned int*)&Al[(size_t)s * PITCH + 2 * cpid] = pk;
            }
        __syncthreads();
        if (k0 + 32 < CCH) {
            if (!wzero) {
                w0 = *(const u16x8*)(wsrc + k0 + 32);
                w1 = *(const u16x8*)(wsrc + k0 + 40);
            }
#pragma unroll
            for (int cc = 0; cc < 2; ++cc)
#pragma unroll
                for (int j = 0; j < 4; ++j) {
                    size_t off = ((size_t)n * CCH + k0 + 32 + 2 * cpid + cc) * TOT_S
                               + sb + 2 * sp + 32 * j;
                    off = off > XLIM ? XLIM : off;
                    ax[cc][j] = *(const float2*)(x + off);
                    ap[cc][j] = *(const float2*)(pos + off);
                }
        }
        short8 af[4], bfr[4];
#pragma unroll
        for (int mt = 0; mt < 4; ++mt)
            af[mt] = *(const short8*)&Wl[(m0 + mt * 16 + row16) * PITCH + q * 8];
#pragma unroll
        for (int nt = 0; nt < 4; ++nt)
            bfr[nt] = *(const short8*)&Al[(n0 + nt * 16 + row16) * PITCH + q * 8];
#pragma unroll
        for (int mt = 0; mt < 4; ++mt)
#pragma unroll
            for (int nt = 0; nt < 4; ++nt)
                acc[mt][nt] = __builtin_amdgcn_mfma_f32_16x16x32_bf16(
                    af[mt], bfr[nt], acc[mt][nt], 0, 0, 0);
        __syncthreads();
    }

#pragma unroll
    for (int nt = 0; nt < 4; ++nt) {
        const int s = sb + n0 + nt * 16 + row16;
        if (s >= TOT_S) continue;
        float* orow = offw + ((size_t)n * TOT_S + s) * 96;
#pragma unroll
        for (int mt = 0; mt < 4; ++mt) {
            const int o = m0 + mt * 16 + q * 4;
            if (o < 96) {
                const float* bsrc = (o < 64) ? (bloc + o) : (bw + o - 64);
                const f32x4 bb = *(const f32x4*)bsrc;
                f32x4 v = acc[mt][nt];
                v[0] += bb[0]; v[1] += bb[1]; v[2] += bb[2]; v[3] += bb[3];
                *(f32x4*)(orow + o) = v;
            }
        }
    }
}

// ---------------------------------------------------------------------------
// Sampling v2: ONE WAVE PER (n,s). lane -> head m = lane>>3, channels
// c = m*64 + (lane&7)*8 .. +8  (== lane*8: output row is one contiguous 1KiB
// store). 16B/lane gathers; branchless clamp + masked corner weights.
// ---------------------------------------------------------------------------
__global__ __launch_bounds__(256)
void sample_attn(const unsigned short* __restrict__ value,  // (N,S,512) bf16
                 const float* __restrict__ offw,            // (N,S,96)
                 const float* __restrict__ vsizes,
                 const float* __restrict__ vscales,
                 unsigned short* __restrict__ samp)         // (N,S,512) bf16
{
    const int lane = threadIdx.x;
    const int item = blockIdx.x * blockDim.y + threadIdx.y;
    const int total = NBATCH * TOT_S;
    if (item >= total) return;
    const int s = item % TOT_S;
    const int n = item / TOT_S;
    const int m = lane >> 3;

    // query level + pixel-center coords (wave-uniform)
    int lvl; float prex, prey;
    if (s < 10000)      { lvl = 0; const int l = s;         const int qq = l / 100; prey = qq + 0.5f; prex = (l - qq * 100) + 0.5f; }
    else if (s < 12500) { lvl = 1; const int l = s - 10000; const int qq = l / 50;  prey = qq + 0.5f; prex = (l - qq * 50)  + 0.5f; }
    else if (s < 13125) { lvl = 2; const int l = s - 12500; const int qq = l / 25;  prey = qq + 0.5f; prex = (l - qq * 25)  + 0.5f; }
    else                { lvl = 3; const int l = s - 13125; const int qq = l / 13;  prey = qq + 0.5f; prex = (l - qq * 13)  + 0.5f; }

    const float* ow = offw + ((size_t)n * TOT_S + s) * 96;

    // per-head softmax over 4 logits (replicated across the 8 lanes of a head)
    const float w0 = ow[64 + m * 4 + 0], w1 = ow[64 + m * 4 + 1];
    const float w2 = ow[64 + m * 4 + 2], w3 = ow[64 + m * 4 + 3];
    const float mx = fmaxf(fmaxf(w0, w1), fmaxf(w2, w3));
    const float e0 = expf(w0 - mx), e1 = expf(w1 - mx), e2 = expf(w2 - mx), e3 = expf(w3 - mx);
    const float inv = 1.f / (e0 + e1 + e2 + e3);
    const float wgt[4] = { e0 * inv, e1 * inv, e2 * inv, e3 * inv };

    const int HS[4]  = { 100, 50, 25, 13 };
    const int WS[4]  = { 100, 50, 25, 13 };
    const int CUR[4] = { 0, 10000, 12500, 13125 };

    const float invsx = 1.f / vsizes[((n * 4) + lvl) * 2 + 0];
    const float invsy = 1.f / vsizes[((n * 4) + lvl) * 2 + 1];
    // channel base: c = lane*8
    const unsigned short* vbase = value + (size_t)n * TOT_S * CCH + lane * 8;

    float acc[8] = {};
#pragma unroll
    for (int f = 0; f < 4; ++f) {
        const float offx = ow[(m * 4 + f) * 2 + 0];
        const float offy = ow[(m * 4 + f) * 2 + 1];
        const float scx = 2.f * vscales[((n * 4) + f) * 2 + 0] * invsx;
        const float scy = 2.f * vscales[((n * 4) + f) * 2 + 1] * invsy;
        const int Wf = WS[f], Hf = HS[f], cf = CUR[f];
        const float xi = (offx + prex) * scx * (Wf * 0.5f) - 0.5f;
        const float yi = (offy + prey) * scy * (Hf * 0.5f) - 0.5f;
        const float x0f = floorf(xi), y0f = floorf(yi);
        const float wx1 = xi - x0f, wy1 = yi - y0f;
        const float wx0 = 1.f - wx1, wy0 = 1.f - wy1;
        const int x0 = (int)x0f, y0 = (int)y0f;
        const bool xin0 = (x0 >= 0) && (x0 < Wf);
        const bool xin1 = (x0 + 1 >= 0) && (x0 + 1 < Wf);
        const bool yin0 = (y0 >= 0) && (y0 < Hf);
        const bool yin1 = (y0 + 1 >= 0) && (y0 + 1 < Hf);
        // masked corner weights (fold level weight in), clamped indices
        const float cw00 = (xin0 && yin0) ? wgt[f] * wx0 * wy0 : 0.f;
        const float cw10 = (xin1 && yin0) ? wgt[f] * wx1 * wy0 : 0.f;
        const float cw01 = (xin0 && yin1) ? wgt[f] * wx0 * wy1 : 0.f;
        const float cw11 = (xin1 && yin1) ? wgt[f] * wx1 * wy1 : 0.f;
        const int x0c = min(max(x0, 0), Wf - 1);
        const int x1c = min(max(x0 + 1, 0), Wf - 1);
        const int y0c = min(max(y0, 0), Hf - 1);
        const int y1c = min(max(y0 + 1, 0), Hf - 1);
        const unsigned short* row0 = vbase + (size_t)(cf + y0c * Wf) * CCH;
        const unsigned short* row1 = vbase + (size_t)(cf + y1c * Wf) * CCH;
        const u16x8 v00 = *(const u16x8*)(row0 + (size_t)x0c * CCH);
        const u16x8 v10 = *(const u16x8*)(row0 + (size_t)x1c * CCH);
        const u16x8 v01 = *(const u16x8*)(row1 + (size_t)x0c * CCH);
        const u16x8 v11 = *(const u16x8*)(row1 + (size_t)x1c * CCH);
#pragma unroll
        for (int j = 0; j < 8; ++j) {
            acc[j] += cw00 * bf2f(v00[j]) + cw10 * bf2f(v10[j])
                    + cw01 * bf2f(v01[j]) + cw11 * bf2f(v11[j]);
        }
    }

    u16x8 ov;
#pragma unroll
    for (int j = 0; j < 8; ++j) ov[j] = f2bf(acc[j]);
    *(u16x8*)(samp + ((size_t)n * TOT_S + s) * CCH + lane * 8) = ov;
}

// ---------------------------------------------------------------------------
// MFMA GEMM 3 v5: 128x128, 8 waves, BK=64 via two 32-wide LDS arrays.
// out[n][o][s] = (sum_c Wo[o][c]*samp[s][c] + bo[o]) * scale[o]
// ---------------------------------------------------------------------------
__global__ __launch_bounds__(512)
void gemm_out_mfma(const unsigned short* __restrict__ Wob,
                   const unsigned short* __restrict__ Sampb,
                   const float* __restrict__ bo, const float* __restrict__ scale,
                   float* __restrict__ out)
{
    __shared__ unsigned short Sl[2][128 * PITCH];
    __shared__ unsigned short Wl[2][128 * PITCH];
    const int n  = blockIdx.z;
    const int ob = blockIdx.y * 128;
    const int sb = blockIdx.x * 128;
    const int tid = threadIdx.x;
    const int r    = tid >> 2;              // 0..127
    const int wh   = (tid & 3) >> 1;        // k-half
    const int segh = (tid & 1) * 16;
    const int sr = min(sb + r, TOT_S - 1);
    const unsigned short* ssrc = Sampb + ((size_t)n * TOT_S + sr) * CCH + wh * 32 + segh;
    const unsigned short* wsrc = Wob + ((size_t)(ob + r)) * CCH + wh * 32 + segh;
    unsigned short* sdst = &Sl[wh][r * PITCH + segh];
    unsigned short* wdst = &Wl[wh][r * PITCH + segh];

    const int wave = tid >> 6, lane = tid & 63;
    const int m0 = (wave & 1) * 64, n0 = (wave >> 1) * 32;
    const int row16 = lane & 15, q = lane >> 4;

    u16x8 s0v = *(const u16x8*)(ssrc);
    u16x8 s1v = *(const u16x8*)(ssrc + 8);
    u16x8 w0v = *(const u16x8*)(wsrc);
    u16x8 w1v = *(const u16x8*)(wsrc + 8);

    f32x4 acc[4][2] = {};
    for (int k0 = 0; k0 < CCH; k0 += 64) {
        *(u16x8*)sdst = s0v; *(u16x8*)(sdst + 8) = s1v;
        *(u16x8*)wdst = w0v; *(u16x8*)(wdst + 8) = w1v;
        __syncthreads();
        if (k0 + 64 < CCH) {
            s0v = *(const u16x8*)(ssrc + k0 + 64);
            s1v = *(const u16x8*)(ssrc + k0 + 72);
            w0v = *(const u16x8*)(wsrc + k0 + 64);
            w1v = *(const u16x8*)(wsrc + k0 + 72);
        }
#pragma unroll
        for (int kh = 0; kh < 2; ++kh) {
            short8 af[4], bfr[2];
#pragma unroll
            for (int mt = 0; mt < 4; ++mt)
                af[mt] = *(const short8*)&Sl[kh][(m0 + mt * 16 + row16) * PITCH + q * 8];
#pragma unroll
            for (int nt = 0; nt < 2; ++nt)
                bfr[nt] = *(const short8*)&Wl[kh][(n0 + nt * 16 + row16) * PITCH + q * 8];
#pragma unroll
            for (int mt = 0; mt < 4; ++mt)
#pragma unroll
                for (int nt = 0; nt < 2; ++nt)
                    acc[mt][nt] = __builtin_amdgcn_mfma_f32_16x16x32_bf16(
                        af[mt], bfr[nt], acc[mt][nt], 0, 0, 0);
        }
        __syncthreads();
    }

#pragma unroll
    for (int nt = 0; nt < 2; ++nt) {
        const int o = ob + n0 + nt * 16 + row16;
        const float bo_ = bo[o];
        const float sc_ = scale[o];
        float* orow = out + ((size_t)n * CCH + o) * (size_t)TOT_S;
#pragma unroll
        for (int mt = 0; mt < 4; ++mt) {
            const int s0 = sb + m0 + mt * 16 + q * 4;
            const f32x4 a = acc[mt][nt];
            if (s0 + 3 < TOT_S) {
                float2 v0 = make_float2((a[0] + bo_) * sc_, (a[1] + bo_) * sc_);
                float2 v1 = make_float2((a[2] + bo_) * sc_, (a[3] + bo_) * sc_);
                *(float2*)(orow + s0) = v0;
                *(float2*)(orow + s0 + 2) = v1;
            } else {
                for (int i = 0; i < 4; ++i)
                    if (s0 + i < TOT_S) orow[s0 + i] = (a[i] + bo_) * sc_;
            }
        }
    }
}

// ---------------------------------------------------------------------------
extern "C" void kernel_launch(void* const* d_in, const int* in_sizes, int n_in,
                              void* d_out, int out_size, void* d_ws, size_t ws_size,
                              hipStream_t stream)
{
    const float* x     = (const float*)d_in[0];
    const float* pos   = (const float*)d_in[1];
    const unsigned char* mask = (const unsigned char*)d_in[2];
    const float* vsz   = (const float*)d_in[3];
    const float* vsc   = (const float*)d_in[4];
    const float* Wv    = (const float*)d_in[5];
    const float* bv    = (const float*)d_in[6];
    const float* Wloc  = (const float*)d_in[7];
    const float* bloc  = (const float*)d_in[8];
    const float* Ww    = (const float*)d_in[9];
    const float* bw    = (const float*)d_in[10];
    const float* Wo    = (const float*)d_in[11];
    const float* bo    = (const float*)d_in[12];
    const float* scale = (const float*)d_in[13];
    float* out = (float*)d_out;

    const size_t SC = (size_t)TOT_S * CCH;
    unsigned short* valb  = (unsigned short*)d_ws;
    unsigned short* sampb = valb  + 2 * SC;
    float* offw = (float*)(sampb + 2 * SC);
    unsigned short* wvb = (unsigned short*)(offw + 2 * (size_t)TOT_S * 96);
    unsigned short* wob = wvb + 512 * 512;
    unsigned short* wlb = wob + 512 * 512;
    unsigned short* wwb = wlb + 64 * 512;

    cast_f32_bf16<<<256, 256, 0, stream>>>(Wv,   wvb, 512 * 512 / 4);
    cast_f32_bf16<<<256, 256, 0, stream>>>(Wo,   wob, 512 * 512 / 4);
    cast_f32_bf16<<<32,  256, 0, stream>>>(Wloc, wlb, 64 * 512 / 4);
    cast_f32_bf16<<<16,  256, 0, stream>>>(Ww,   wwb, 32 * 512 / 4);

    const int sTiles = (TOT_S + 127) / 128;  // 104

    gemm_value_mfma<<<dim3(sTiles, CCH / 128, NBATCH), 512, 0, stream>>>(
        wvb, x, bv, mask, valb);
    gemm_offw_mfma<<<dim3(sTiles, 1, NBATCH), 256, 0, stream>>>(
        wlb, wwb, bloc, bw, x, pos, mask, offw);

    const int items = NBATCH * TOT_S;   // one wave per (n,s)
    sample_attn<<<(items + 3) / 4, dim3(64, 4), 0, stream>>>(valb, offw, vsz, vsc, sampb);

    gemm_out_mfma<<<dim3(sTiles, CCH / 128, NBATCH), 512, 0, stream>>>(
        wob, sampb, bo, scale, out);
}

// Round 12
// 285.161 us; speedup vs baseline: 1.0202x; 1.0089x over previous
//
#include <hip/hip_runtime.h>
#include <math.h>

#define TOT_S   13294
#define NBATCH  2
#define CCH     512
#define MHEAD   8
#define PITCH   40   // LDS row pitch in bf16 elems (32 + 8 pad -> 80B)

typedef short     short8  __attribute__((ext_vector_type(8)));
typedef float     f32x4   __attribute__((ext_vector_type(4)));
typedef unsigned short u16x8 __attribute__((ext_vector_type(8)));
typedef unsigned short u16x4 __attribute__((ext_vector_type(4)));

__device__ __forceinline__ unsigned short f2bf(float f) {
    union { float f; unsigned int u; } v; v.f = f;
    unsigned int r = v.u + 0x7fffu + ((v.u >> 16) & 1u);   // RNE
    return (unsigned short)(r >> 16);
}
__device__ __forceinline__ float bf2f(unsigned short h) {
    union { unsigned int u; float f; } v; v.u = ((unsigned int)h) << 16;
    return v.f;
}

// ---------------------------------------------------------------------------
__global__ void cast_f32_bf16(const float* __restrict__ src,
                              unsigned short* __restrict__ dst, int n4)
{
    const int i = blockIdx.x * blockDim.x + threadIdx.x;
    if (i < n4) {
        const float4 v = *(const float4*)(src + (size_t)i * 4);
        u16x4 o;
        o[0] = f2bf(v.x); o[1] = f2bf(v.y); o[2] = f2bf(v.z); o[3] = f2bf(v.w);
        *(u16x4*)(dst + (size_t)i * 4) = o;
    }
}

// ---------------------------------------------------------------------------
// FUSED MFMA GEMM: blockIdx.y < 4  -> value GEMM o-tile (v10 BK=64 logic)
//                  blockIdx.y == 4 -> offsets+logits GEMM (96-row W, x+pos,
//                                     mask folded at staging, f32 epilogue)
// One launch, 1040 blocks: offw work co-schedules with value blocks (its
// previous standalone launch was 208 blocks = <1 block/CU, ~80% idle CUs),
// and shares the x s-tile reads via the same-XCD L2 (y-stride 104 % 8 == 0).
// ---------------------------------------------------------------------------
__global__ __launch_bounds__(512)
void gemm_val_offw_mfma(const unsigned short* __restrict__ Wb,
                        const unsigned short* __restrict__ Wlb,
                        const unsigned short* __restrict__ Wwb,
                        const float* __restrict__ bv,
                        const float* __restrict__ bloc,
                        const float* __restrict__ bw,
                        const float* __restrict__ x,
                        const float* __restrict__ pos,
                        const unsigned char* __restrict__ mask,
                        unsigned short* __restrict__ valb,
                        float* __restrict__ offw)
{
    __shared__ unsigned short Wl[2][128 * PITCH];   // k-halves, 2 x 10 KB
    __shared__ unsigned short Al[2][128 * PITCH];
    const int n  = blockIdx.z;
    const int oby = blockIdx.y;
    const int sb = blockIdx.x * 128;
    const int tid = threadIdx.x;

    // common staging geometry
    const int r    = tid >> 2;              // 0..127
    const int wh   = (tid & 3) >> 1;        // k-half 0/1
    const int segh = (tid & 1) * 16;        // 0 or 16 within half
    const int sp   = tid & 15;              // s-pair
    const int cgrp = (tid >> 4) & 15;       // k-pair within half
    const int half = tid >> 8;              // j = 2*half + jj
    const size_t XLIM = (size_t)NBATCH * CCH * TOT_S - 2;

    const int wave = tid >> 6, lane = tid & 63;
    const int m0 = (wave & 1) * 64, n0 = (wave >> 1) * 32;
    const int row16 = lane & 15, q = lane >> 4;

    if (oby < 4) {
        // =============== VALUE branch (v10 logic, verified) ===============
        const int ob = oby * 128;
        const unsigned short* wsrc = Wb + ((size_t)(ob + r)) * CCH + wh * 32 + segh;
        unsigned short* wdst = &Wl[wh][r * PITCH + segh];

        u16x8 w0 = *(const u16x8*)(wsrc);
        u16x8 w1 = *(const u16x8*)(wsrc + 8);
        float2 ax[2][2][2];   // [kh][cc][jj]
#pragma unroll
        for (int kh = 0; kh < 2; ++kh)
#pragma unroll
            for (int cc = 0; cc < 2; ++cc)
#pragma unroll
                for (int jj = 0; jj < 2; ++jj) {
                    size_t off = ((size_t)n * CCH + kh * 32 + 2 * cgrp + cc) * TOT_S
                               + sb + 2 * sp + 32 * (2 * half + jj);
                    off = off > XLIM ? XLIM : off;
                    ax[kh][cc][jj] = *(const float2*)(x + off);
                }

        f32x4 acc[4][2] = {};
        for (int k0 = 0; k0 < CCH; k0 += 64) {
            *(u16x8*)wdst = w0; *(u16x8*)(wdst + 8) = w1;
#pragma unroll
            for (int kh = 0; kh < 2; ++kh)
#pragma unroll
                for (int jj = 0; jj < 2; ++jj)
#pragma unroll
                    for (int i = 0; i < 2; ++i) {
                        const int s = 2 * sp + 32 * (2 * half + jj) + i;
                        const float lo = i ? ax[kh][0][jj].y : ax[kh][0][jj].x;
                        const float hi = i ? ax[kh][1][jj].y : ax[kh][1][jj].x;
                        *(unsigned int*)&Al[kh][(size_t)s * PITCH + 2 * cgrp] =
                            (unsigned int)f2bf(lo) | ((unsigned int)f2bf(hi) << 16);
                    }
            __syncthreads();
            if (k0 + 64 < CCH) {
                w0 = *(const u16x8*)(wsrc + k0 + 64);
                w1 = *(const u16x8*)(wsrc + k0 + 72);
#pragma unroll
                for (int kh = 0; kh < 2; ++kh)
#pragma unroll
                    for (int cc = 0; cc < 2; ++cc)
#pragma unroll
                        for (int jj = 0; jj < 2; ++jj) {
                            size_t off = ((size_t)n * CCH + k0 + 64 + kh * 32
                                          + 2 * cgrp + cc) * TOT_S
                                       + sb + 2 * sp + 32 * (2 * half + jj);
                            off = off > XLIM ? XLIM : off;
                            ax[kh][cc][jj] = *(const float2*)(x + off);
                        }
            }
#pragma unroll
            for (int kh = 0; kh < 2; ++kh) {
                short8 af[4], bfr[2];
#pragma unroll
                for (int mt = 0; mt < 4; ++mt)
                    af[mt] = *(const short8*)&Wl[kh][(m0 + mt * 16 + row16) * PITCH + q * 8];
#pragma unroll
                for (int nt = 0; nt < 2; ++nt)
                    bfr[nt] = *(const short8*)&Al[kh][(n0 + nt * 16 + row16) * PITCH + q * 8];
#pragma unroll
                for (int mt = 0; mt < 4; ++mt)
#pragma unroll
                    for (int nt = 0; nt < 2; ++nt)
                        acc[mt][nt] = __builtin_amdgcn_mfma_f32_16x16x32_bf16(
                            af[mt], bfr[nt], acc[mt][nt], 0, 0, 0);
            }
            __syncthreads();
        }

#pragma unroll
        for (int nt = 0; nt < 2; ++nt) {
            const int s = sb + n0 + nt * 16 + row16;
            if (s >= TOT_S) continue;
            const float msk = mask[(size_t)n * TOT_S + s] ? 0.f : 1.f;
            unsigned short* orow = valb + ((size_t)n * TOT_S + s) * CCH + ob + m0;
#pragma unroll
            for (int mt = 0; mt < 4; ++mt) {
                const f32x4 bvv = *(const f32x4*)(bv + ob + m0 + mt * 16 + q * 4);
                const f32x4 a = acc[mt][nt];
                u16x4 ov;
                ov[0] = f2bf((a[0] + bvv[0]) * msk);
                ov[1] = f2bf((a[1] + bvv[1]) * msk);
                ov[2] = f2bf((a[2] + bvv[2]) * msk);
                ov[3] = f2bf((a[3] + bvv[3]) * msk);
                *(u16x4*)(orow + mt * 16 + q * 4) = ov;
            }
        }
    } else {
        // =============== OFFW branch (96-row W, x+pos, masked) ===============
        const bool wz = (r >= 96);
        const unsigned short* wsrc =
            (r < 64) ? (Wlb + (size_t)r * CCH + wh * 32 + segh)
                     : (Wwb + (size_t)((r < 96 ? r : 95) - 64) * CCH + wh * 32 + segh);
        unsigned short* wdst = &Wl[wh][r * PITCH + segh];

        float mkm[4];   // [jj*2+i]
#pragma unroll
        for (int jj = 0; jj < 2; ++jj)
#pragma unroll
            for (int i = 0; i < 2; ++i) {
                const int s = sb + 2 * sp + 32 * (2 * half + jj) + i;
                const int sc = s < TOT_S ? s : TOT_S - 1;
                mkm[jj * 2 + i] = mask[(size_t)n * TOT_S + sc] ? 0.f : 1.f;
            }

        u16x8 w0 = {}, w1 = {};
        if (!wz) { w0 = *(const u16x8*)(wsrc); w1 = *(const u16x8*)(wsrc + 8); }
        float2 ax[2][2][2], ap[2][2][2];
#pragma unroll
        for (int kh = 0; kh < 2; ++kh)
#pragma unroll
            for (int cc = 0; cc < 2; ++cc)
#pragma unroll
                for (int jj = 0; jj < 2; ++jj) {
                    size_t off = ((size_t)n * CCH + kh * 32 + 2 * cgrp + cc) * TOT_S
                               + sb + 2 * sp + 32 * (2 * half + jj);
                    off = off > XLIM ? XLIM : off;
                    ax[kh][cc][jj] = *(const float2*)(x + off);
                    ap[kh][cc][jj] = *(const float2*)(pos + off);
                }

        f32x4 acc[4][2] = {};
        for (int k0 = 0; k0 < CCH; k0 += 64) {
            *(u16x8*)wdst = w0; *(u16x8*)(wdst + 8) = w1;
#pragma unroll
            for (int kh = 0; kh < 2; ++kh)
#pragma unroll
                for (int jj = 0; jj < 2; ++jj)
#pragma unroll
                    for (int i = 0; i < 2; ++i) {
                        const int s = 2 * sp + 32 * (2 * half + jj) + i;
                        const float lo = (i ? ax[kh][0][jj].y + ap[kh][0][jj].y
                                            : ax[kh][0][jj].x + ap[kh][0][jj].x)
                                         * mkm[jj * 2 + i];
                        const float hi = (i ? ax[kh][1][jj].y + ap[kh][1][jj].y
                                            : ax[kh][1][jj].x + ap[kh][1][jj].x)
                                         * mkm[jj * 2 + i];
                        *(unsigned int*)&Al[kh][(size_t)s * PITCH + 2 * cgrp] =
                            (unsigned int)f2bf(lo) | ((unsigned int)f2bf(hi) << 16);
                    }
            __syncthreads();
            if (k0 + 64 < CCH) {
                if (!wz) {
                    w0 = *(const u16x8*)(wsrc + k0 + 64);
                    w1 = *(const u16x8*)(wsrc + k0 + 72);
                }
#pragma unroll
                for (int kh = 0; kh < 2; ++kh)
#pragma unroll
                    for (int cc = 0; cc < 2; ++cc)
#pragma unroll
                        for (int jj = 0; jj < 2; ++jj) {
                            size_t off = ((size_t)n * CCH + k0 + 64 + kh * 32
                                          + 2 * cgrp + cc) * TOT_S
                                       + sb + 2 * sp + 32 * (2 * half + jj);
                            off = off > XLIM ? XLIM : off;
                            ax[kh][cc][jj] = *(const float2*)(x + off);
                            ap[kh][cc][jj] = *(const float2*)(pos + off);
                        }
            }
#pragma unroll
            for (int kh = 0; kh < 2; ++kh) {
                short8 af[4], bfr[2];
#pragma unroll
                for (int mt = 0; mt < 4; ++mt)
                    af[mt] = *(const short8*)&Wl[kh][(m0 + mt * 16 + row16) * PITCH + q * 8];
#pragma unroll
                for (int nt = 0; nt < 2; ++nt)
                    bfr[nt] = *(const short8*)&Al[kh][(n0 + nt * 16 + row16) * PITCH + q * 8];
#pragma unroll
                for (int mt = 0; mt < 4; ++mt)
#pragma unroll
                    for (int nt = 0; nt < 2; ++nt)
                        acc[mt][nt] = __builtin_amdgcn_mfma_f32_16x16x32_bf16(
                            af[mt], bfr[nt], acc[mt][nt], 0, 0, 0);
            }
            __syncthreads();
        }

#pragma unroll
        for (int nt = 0; nt < 2; ++nt) {
            const int s = sb + n0 + nt * 16 + row16;
            if (s >= TOT_S) continue;
            float* orow = offw + ((size_t)n * TOT_S + s) * 96;
#pragma unroll
            for (int mt = 0; mt < 4; ++mt) {
                const int o = m0 + mt * 16 + q * 4;
                if (o < 96) {
                    const float* bsrc = (o < 64) ? (bloc + o) : (bw + o - 64);
                    const f32x4 bb = *(const f32x4*)bsrc;
                    f32x4 v = acc[mt][nt];
                    v[0] += bb[0]; v[1] += bb[1]; v[2] += bb[2]; v[3] += bb[3];
                    *(f32x4*)(orow + o) = v;
                }
            }
        }
    }
}

// ---------------------------------------------------------------------------
// Sampling v2: ONE WAVE PER (n,s). lane -> head m = lane>>3, channels
// c = m*64 + (lane&7)*8 .. +8  (== lane*8: output row is one contiguous 1KiB
// store). 16B/lane gathers; branchless clamp + masked corner weights.
// ---------------------------------------------------------------------------
__global__ __launch_bounds__(256)
void sample_attn(const unsigned short* __restrict__ value,  // (N,S,512) bf16
                 const float* __restrict__ offw,            // (N,S,96)
                 const float* __restrict__ vsizes,
                 const float* __restrict__ vscales,
                 unsigned short* __restrict__ samp)         // (N,S,512) bf16
{
    const int lane = threadIdx.x;
    const int item = blockIdx.x * blockDim.y + threadIdx.y;
    const int total = NBATCH * TOT_S;
    if (item >= total) return;
    const int s = item % TOT_S;
    const int n = item / TOT_S;
    const int m = lane >> 3;

    // query level + pixel-center coords (wave-uniform)
    int lvl; float prex, prey;
    if (s < 10000)      { lvl = 0; const int l = s;         const int qq = l / 100; prey = qq + 0.5f; prex = (l - qq * 100) + 0.5f; }
    else if (s < 12500) { lvl = 1; const int l = s - 10000; const int qq = l / 50;  prey = qq + 0.5f; prex = (l - qq * 50)  + 0.5f; }
    else if (s < 13125) { lvl = 2; const int l = s - 12500; const int qq = l / 25;  prey = qq + 0.5f; prex = (l - qq * 25)  + 0.5f; }
    else                { lvl = 3; const int l = s - 13125; const int qq = l / 13;  prey = qq + 0.5f; prex = (l - qq * 13)  + 0.5f; }

    const float* ow = offw + ((size_t)n * TOT_S + s) * 96;

    // per-head softmax over 4 logits (replicated across the 8 lanes of a head)
    const float w0 = ow[64 + m * 4 + 0], w1 = ow[64 + m * 4 + 1];
    const float w2 = ow[64 + m * 4 + 2], w3 = ow[64 + m * 4 + 3];
    const float mx = fmaxf(fmaxf(w0, w1), fmaxf(w2, w3));
    const float e0 = expf(w0 - mx), e1 = expf(w1 - mx), e2 = expf(w2 - mx), e3 = expf(w3 - mx);
    const float inv = 1.f / (e0 + e1 + e2 + e3);
    const float wgt[4] = { e0 * inv, e1 * inv, e2 * inv, e3 * inv };

    const int HS[4]  = { 100, 50, 25, 13 };
    const int WS[4]  = { 100, 50, 25, 13 };
    const int CUR[4] = { 0, 10000, 12500, 13125 };

    const float invsx = 1.f / vsizes[((n * 4) + lvl) * 2 + 0];
    const float invsy = 1.f / vsizes[((n * 4) + lvl) * 2 + 1];
    // channel base: c = lane*8
    const unsigned short* vbase = value + (size_t)n * TOT_S * CCH + lane * 8;

    float acc[8] = {};
#pragma unroll
    for (int f = 0; f < 4; ++f) {
        const float offx = ow[(m * 4 + f) * 2 + 0];
        const float offy = ow[(m * 4 + f) * 2 + 1];
        const float scx = 2.f * vscales[((n * 4) + f) * 2 + 0] * invsx;
        const float scy = 2.f * vscales[((n * 4) + f) * 2 + 1] * invsy;
        const int Wf = WS[f], Hf = HS[f], cf = CUR[f];
        const float xi = (offx + prex) * scx * (Wf * 0.5f) - 0.5f;
        const float yi = (offy + prey) * scy * (Hf * 0.5f) - 0.5f;
        const float x0f = floorf(xi), y0f = floorf(yi);
        const float wx1 = xi - x0f, wy1 = yi - y0f;
        const float wx0 = 1.f - wx1, wy0 = 1.f - wy1;
        const int x0 = (int)x0f, y0 = (int)y0f;
        const bool xin0 = (x0 >= 0) && (x0 < Wf);
        const bool xin1 = (x0 + 1 >= 0) && (x0 + 1 < Wf);
        const bool yin0 = (y0 >= 0) && (y0 < Hf);
        const bool yin1 = (y0 + 1 >= 0) && (y0 + 1 < Hf);
        // masked corner weights (fold level weight in), clamped indices
        const float cw00 = (xin0 && yin0) ? wgt[f] * wx0 * wy0 : 0.f;
        const float cw10 = (xin1 && yin0) ? wgt[f] * wx1 * wy0 : 0.f;
        const float cw01 = (xin0 && yin1) ? wgt[f] * wx0 * wy1 : 0.f;
        const float cw11 = (xin1 && yin1) ? wgt[f] * wx1 * wy1 : 0.f;
        const int x0c = min(max(x0, 0), Wf - 1);
        const int x1c = min(max(x0 + 1, 0), Wf - 1);
        const int y0c = min(max(y0, 0), Hf - 1);
        const int y1c = min(max(y0 + 1, 0), Hf - 1);
        const unsigned short* row0 = vbase + (size_t)(cf + y0c * Wf) * CCH;
        const unsigned short* row1 = vbase + (size_t)(cf + y1c * Wf) * CCH;
        const u16x8 v00 = *(const u16x8*)(row0 + (size_t)x0c * CCH);
        const u16x8 v10 = *(const u16x8*)(row0 + (size_t)x1c * CCH);
        const u16x8 v01 = *(const u16x8*)(row1 + (size_t)x0c * CCH);
        const u16x8 v11 = *(const u16x8*)(row1 + (size_t)x1c * CCH);
#pragma unroll
        for (int j = 0; j < 8; ++j) {
            acc[j] += cw00 * bf2f(v00[j]) + cw10 * bf2f(v10[j])
                    + cw01 * bf2f(v01[j]) + cw11 * bf2f(v11[j]);
        }
    }

    u16x8 ov;
#pragma unroll
    for (int j = 0; j < 8; ++j) ov[j] = f2bf(acc[j]);
    *(u16x8*)(samp + ((size_t)n * TOT_S + s) * CCH + lane * 8) = ov;
}

// ---------------------------------------------------------------------------
// MFMA GEMM 3 v5: 128x128, 8 waves, BK=64 via two 32-wide LDS arrays.
// out[n][o][s] = (sum_c Wo[o][c]*samp[s][c] + bo[o]) * scale[o]
// ---------------------------------------------------------------------------
__global__ __launch_bounds__(512)
void gemm_out_mfma(const unsigned short* __restrict__ Wob,
                   const unsigned short* __restrict__ Sampb,
                   const float* __restrict__ bo, const float* __restrict__ scale,
                   float* __restrict__ out)
{
    __shared__ unsigned short Sl[2][128 * PITCH];
    __shared__ unsigned short Wl[2][128 * PITCH];
    const int n  = blockIdx.z;
    const int ob = blockIdx.y * 128;
    const int sb = blockIdx.x * 128;
    const int tid = threadIdx.x;
    const int r    = tid >> 2;              // 0..127
    const int wh   = (tid & 3) >> 1;        // k-half
    const int segh = (tid & 1) * 16;
    const int sr = min(sb + r, TOT_S - 1);
    const unsigned short* ssrc = Sampb + ((size_t)n * TOT_S + sr) * CCH + wh * 32 + segh;
    const unsigned short* wsrc = Wob + ((size_t)(ob + r)) * CCH + wh * 32 + segh;
    unsigned short* sdst = &Sl[wh][r * PITCH + segh];
    unsigned short* wdst = &Wl[wh][r * PITCH + segh];

    const int wave = tid >> 6, lane = tid & 63;
    const int m0 = (wave & 1) * 64, n0 = (wave >> 1) * 32;
    const int row16 = lane & 15, q = lane >> 4;

    u16x8 s0v = *(const u16x8*)(ssrc);
    u16x8 s1v = *(const u16x8*)(ssrc + 8);
    u16x8 w0v = *(const u16x8*)(wsrc);
    u16x8 w1v = *(const u16x8*)(wsrc + 8);

    f32x4 acc[4][2] = {};
    for (int k0 = 0; k0 < CCH; k0 += 64) {
        *(u16x8*)sdst = s0v; *(u16x8*)(sdst + 8) = s1v;
        *(u16x8*)wdst = w0v; *(u16x8*)(wdst + 8) = w1v;
        __syncthreads();
        if (k0 + 64 < CCH) {
            s0v = *(const u16x8*)(ssrc + k0 + 64);
            s1v = *(const u16x8*)(ssrc + k0 + 72);
            w0v = *(const u16x8*)(wsrc + k0 + 64);
            w1v = *(const u16x8*)(wsrc + k0 + 72);
        }
#pragma unroll
        for (int kh = 0; kh < 2; ++kh) {
            short8 af[4], bfr[2];
#pragma unroll
            for (int mt = 0; mt < 4; ++mt)
                af[mt] = *(const short8*)&Sl[kh][(m0 + mt * 16 + row16) * PITCH + q * 8];
#pragma unroll
            for (int nt = 0; nt < 2; ++nt)
                bfr[nt] = *(const short8*)&Wl[kh][(n0 + nt * 16 + row16) * PITCH + q * 8];
#pragma unroll
            for (int mt = 0; mt < 4; ++mt)
#pragma unroll
                for (int nt = 0; nt < 2; ++nt)
                    acc[mt][nt] = __builtin_amdgcn_mfma_f32_16x16x32_bf16(
                        af[mt], bfr[nt], acc[mt][nt], 0, 0, 0);
        }
        __syncthreads();
    }

#pragma unroll
    for (int nt = 0; nt < 2; ++nt) {
        const int o = ob + n0 + nt * 16 + row16;
        const float bo_ = bo[o];
        const float sc_ = scale[o];
        float* orow = out + ((size_t)n * CCH + o) * (size_t)TOT_S;
#pragma unroll
        for (int mt = 0; mt < 4; ++mt) {
            const int s0 = sb + m0 + mt * 16 + q * 4;
            const f32x4 a = acc[mt][nt];
            if (s0 + 3 < TOT_S) {
                float2 v0 = make_float2((a[0] + bo_) * sc_, (a[1] + bo_) * sc_);
                float2 v1 = make_float2((a[2] + bo_) * sc_, (a[3] + bo_) * sc_);
                *(float2*)(orow + s0) = v0;
                *(float2*)(orow + s0 + 2) = v1;
            } else {
                for (int i = 0; i < 4; ++i)
                    if (s0 + i < TOT_S) orow[s0 + i] = (a[i] + bo_) * sc_;
            }
        }
    }
}

// ---------------------------------------------------------------------------
extern "C" void kernel_launch(void* const* d_in, const int* in_sizes, int n_in,
                              void* d_out, int out_size, void* d_ws, size_t ws_size,
                              hipStream_t stream)
{
    const float* x     = (const float*)d_in[0];
    const float* pos   = (const float*)d_in[1];
    const unsigned char* mask = (const unsigned char*)d_in[2];
    const float* vsz   = (const float*)d_in[3];
    const float* vsc   = (const float*)d_in[4];
    const float* Wv    = (const float*)d_in[5];
    const float* bv    = (const float*)d_in[6];
    const float* Wloc  = (const float*)d_in[7];
    const float* bloc  = (const float*)d_in[8];
    const float* Ww    = (const float*)d_in[9];
    const float* bw    = (const float*)d_in[10];
    const float* Wo    = (const float*)d_in[11];
    const float* bo    = (const float*)d_in[12];
    const float* scale = (const float*)d_in[13];
    float* out = (float*)d_out;

    const size_t SC = (size_t)TOT_S * CCH;
    unsigned short* valb  = (unsigned short*)d_ws;
    unsigned short* sampb = valb  + 2 * SC;
    float* offw = (float*)(sampb + 2 * SC);
    unsigned short* wvb = (unsigned short*)(offw + 2 * (size_t)TOT_S * 96);
    unsigned short* wob = wvb + 512 * 512;
    unsigned short* wlb = wob + 512 * 512;
    unsigned short* wwb = wlb + 64 * 512;

    cast_f32_bf16<<<256, 256, 0, stream>>>(Wv,   wvb, 512 * 512 / 4);
    cast_f32_bf16<<<256, 256, 0, stream>>>(Wo,   wob, 512 * 512 / 4);
    cast_f32_bf16<<<32,  256, 0, stream>>>(Wloc, wlb, 64 * 512 / 4);
    cast_f32_bf16<<<16,  256, 0, stream>>>(Ww,   wwb, 32 * 512 / 4);

    const int sTiles = (TOT_S + 127) / 128;  // 104

    gemm_val_offw_mfma<<<dim3(sTiles, 5, NBATCH), 512, 0, stream>>>(
        wvb, wlb, wwb, bv, bloc, bw, x, pos, mask, valb, offw);

    const int items = NBATCH * TOT_S;   // one wave per (n,s)
    sample_attn<<<(items + 3) / 4, dim3(64, 4), 0, stream>>>(valb, offw, vsz, vsc, sampb);

    gemm_out_mfma<<<dim3(sTiles, CCH / 128, NBATCH), 512, 0, stream>>>(
        wob, sampb, bo, scale, out);
}

// Round 13
// 277.894 us; speedup vs baseline: 1.0469x; 1.0262x over previous
//
#include <hip/hip_runtime.h>
#include <math.h>

#define TOT_S   13294
#define NBATCH  2
#define CCH     512
#define MHEAD   8
#define PITCH   40   // LDS row pitch in bf16 elems (32 + 8 pad -> 80B)

typedef short     short8  __attribute__((ext_vector_type(8)));
typedef float     f32x4   __attribute__((ext_vector_type(4)));
typedef unsigned short u16x8 __attribute__((ext_vector_type(8)));
typedef unsigned short u16x4 __attribute__((ext_vector_type(4)));

typedef __attribute__((address_space(1))) const unsigned int glb_u32;
typedef __attribute__((address_space(3))) unsigned int lds_u32;

__device__ __forceinline__ unsigned short f2bf(float f) {
    union { float f; unsigned int u; } v; v.f = f;
    unsigned int r = v.u + 0x7fffu + ((v.u >> 16) & 1u);   // RNE
    return (unsigned short)(r >> 16);
}
__device__ __forceinline__ float bf2f(unsigned short h) {
    union { unsigned int u; float f; } v; v.u = ((unsigned int)h) << 16;
    return v.f;
}

// ---------------------------------------------------------------------------
// One kernel for all 4 weight casts (removes 3 launches).
// quad ranges: [0,65536) Wv  [65536,131072) Wo  [131072,139264) Wloc
//              [139264,143360) Ww
// ---------------------------------------------------------------------------
__global__ __launch_bounds__(256)
void cast_all_f32_bf16(const float* __restrict__ Wv, const float* __restrict__ Wo,
                       const float* __restrict__ Wloc, const float* __restrict__ Ww,
                       unsigned short* __restrict__ wvb, unsigned short* __restrict__ wob,
                       unsigned short* __restrict__ wlb, unsigned short* __restrict__ wwb)
{
    const int i = blockIdx.x * blockDim.x + threadIdx.x;
    const float* src; unsigned short* dst; int base;
    if      (i < 65536)  { src = Wv;   dst = wvb; base = 0; }
    else if (i < 131072) { src = Wo;   dst = wob; base = 65536; }
    else if (i < 139264) { src = Wloc; dst = wlb; base = 131072; }
    else if (i < 143360) { src = Ww;   dst = wwb; base = 139264; }
    else return;
    const int j = i - base;
    const float4 v = *(const float4*)(src + (size_t)j * 4);
    u16x4 o;
    o[0] = f2bf(v.x); o[1] = f2bf(v.y); o[2] = f2bf(v.z); o[3] = f2bf(v.w);
    *(u16x4*)(dst + (size_t)j * 4) = o;
}

// ---------------------------------------------------------------------------
// FUSED MFMA GEMM (unchanged from r12): blockIdx.y<4 -> value; ==4 -> offw.
// ---------------------------------------------------------------------------
__global__ __launch_bounds__(512)
void gemm_val_offw_mfma(const unsigned short* __restrict__ Wb,
                        const unsigned short* __restrict__ Wlb,
                        const unsigned short* __restrict__ Wwb,
                        const float* __restrict__ bv,
                        const float* __restrict__ bloc,
                        const float* __restrict__ bw,
                        const float* __restrict__ x,
                        const float* __restrict__ pos,
                        const unsigned char* __restrict__ mask,
                        unsigned short* __restrict__ valb,
                        float* __restrict__ offw)
{
    __shared__ unsigned short Wl[2][128 * PITCH];   // k-halves, 2 x 10 KB
    __shared__ unsigned short Al[2][128 * PITCH];
    const int n  = blockIdx.z;
    const int oby = blockIdx.y;
    const int sb = blockIdx.x * 128;
    const int tid = threadIdx.x;

    const int r    = tid >> 2;              // 0..127
    const int wh   = (tid & 3) >> 1;        // k-half 0/1
    const int segh = (tid & 1) * 16;        // 0 or 16 within half
    const int sp   = tid & 15;              // s-pair
    const int cgrp = (tid >> 4) & 15;       // k-pair within half
    const int half = tid >> 8;              // j = 2*half + jj
    const size_t XLIM = (size_t)NBATCH * CCH * TOT_S - 2;

    const int wave = tid >> 6, lane = tid & 63;
    const int m0 = (wave & 1) * 64, n0 = (wave >> 1) * 32;
    const int row16 = lane & 15, q = lane >> 4;

    if (oby < 4) {
        const int ob = oby * 128;
        const unsigned short* wsrc = Wb + ((size_t)(ob + r)) * CCH + wh * 32 + segh;
        unsigned short* wdst = &Wl[wh][r * PITCH + segh];

        u16x8 w0 = *(const u16x8*)(wsrc);
        u16x8 w1 = *(const u16x8*)(wsrc + 8);
        float2 ax[2][2][2];   // [kh][cc][jj]
#pragma unroll
        for (int kh = 0; kh < 2; ++kh)
#pragma unroll
            for (int cc = 0; cc < 2; ++cc)
#pragma unroll
                for (int jj = 0; jj < 2; ++jj) {
                    size_t off = ((size_t)n * CCH + kh * 32 + 2 * cgrp + cc) * TOT_S
                               + sb + 2 * sp + 32 * (2 * half + jj);
                    off = off > XLIM ? XLIM : off;
                    ax[kh][cc][jj] = *(const float2*)(x + off);
                }

        f32x4 acc[4][2] = {};
        for (int k0 = 0; k0 < CCH; k0 += 64) {
            *(u16x8*)wdst = w0; *(u16x8*)(wdst + 8) = w1;
#pragma unroll
            for (int kh = 0; kh < 2; ++kh)
#pragma unroll
                for (int jj = 0; jj < 2; ++jj)
#pragma unroll
                    for (int i = 0; i < 2; ++i) {
                        const int s = 2 * sp + 32 * (2 * half + jj) + i;
                        const float lo = i ? ax[kh][0][jj].y : ax[kh][0][jj].x;
                        const float hi = i ? ax[kh][1][jj].y : ax[kh][1][jj].x;
                        *(unsigned int*)&Al[kh][(size_t)s * PITCH + 2 * cgrp] =
                            (unsigned int)f2bf(lo) | ((unsigned int)f2bf(hi) << 16);
                    }
            __syncthreads();
            if (k0 + 64 < CCH) {
                w0 = *(const u16x8*)(wsrc + k0 + 64);
                w1 = *(const u16x8*)(wsrc + k0 + 72);
#pragma unroll
                for (int kh = 0; kh < 2; ++kh)
#pragma unroll
                    for (int cc = 0; cc < 2; ++cc)
#pragma unroll
                        for (int jj = 0; jj < 2; ++jj) {
                            size_t off = ((size_t)n * CCH + k0 + 64 + kh * 32
                                          + 2 * cgrp + cc) * TOT_S
                                       + sb + 2 * sp + 32 * (2 * half + jj);
                            off = off > XLIM ? XLIM : off;
                            ax[kh][cc][jj] = *(const float2*)(x + off);
                        }
            }
#pragma unroll
            for (int kh = 0; kh < 2; ++kh) {
                short8 af[4], bfr[2];
#pragma unroll
                for (int mt = 0; mt < 4; ++mt)
                    af[mt] = *(const short8*)&Wl[kh][(m0 + mt * 16 + row16) * PITCH + q * 8];
#pragma unroll
                for (int nt = 0; nt < 2; ++nt)
                    bfr[nt] = *(const short8*)&Al[kh][(n0 + nt * 16 + row16) * PITCH + q * 8];
#pragma unroll
                for (int mt = 0; mt < 4; ++mt)
#pragma unroll
                    for (int nt = 0; nt < 2; ++nt)
                        acc[mt][nt] = __builtin_amdgcn_mfma_f32_16x16x32_bf16(
                            af[mt], bfr[nt], acc[mt][nt], 0, 0, 0);
            }
            __syncthreads();
        }

#pragma unroll
        for (int nt = 0; nt < 2; ++nt) {
            const int s = sb + n0 + nt * 16 + row16;
            if (s >= TOT_S) continue;
            const float msk = mask[(size_t)n * TOT_S + s] ? 0.f : 1.f;
            unsigned short* orow = valb + ((size_t)n * TOT_S + s) * CCH + ob + m0;
#pragma unroll
            for (int mt = 0; mt < 4; ++mt) {
                const f32x4 bvv = *(const f32x4*)(bv + ob + m0 + mt * 16 + q * 4);
                const f32x4 a = acc[mt][nt];
                u16x4 ov;
                ov[0] = f2bf((a[0] + bvv[0]) * msk);
                ov[1] = f2bf((a[1] + bvv[1]) * msk);
                ov[2] = f2bf((a[2] + bvv[2]) * msk);
                ov[3] = f2bf((a[3] + bvv[3]) * msk);
                *(u16x4*)(orow + mt * 16 + q * 4) = ov;
            }
        }
    } else {
        const bool wz = (r >= 96);
        const unsigned short* wsrc =
            (r < 64) ? (Wlb + (size_t)r * CCH + wh * 32 + segh)
                     : (Wwb + (size_t)((r < 96 ? r : 95) - 64) * CCH + wh * 32 + segh);
        unsigned short* wdst = &Wl[wh][r * PITCH + segh];

        float mkm[4];
#pragma unroll
        for (int jj = 0; jj < 2; ++jj)
#pragma unroll
            for (int i = 0; i < 2; ++i) {
                const int s = sb + 2 * sp + 32 * (2 * half + jj) + i;
                const int sc = s < TOT_S ? s : TOT_S - 1;
                mkm[jj * 2 + i] = mask[(size_t)n * TOT_S + sc] ? 0.f : 1.f;
            }

        u16x8 w0 = {}, w1 = {};
        if (!wz) { w0 = *(const u16x8*)(wsrc); w1 = *(const u16x8*)(wsrc + 8); }
        float2 ax[2][2][2], ap[2][2][2];
#pragma unroll
        for (int kh = 0; kh < 2; ++kh)
#pragma unroll
            for (int cc = 0; cc < 2; ++cc)
#pragma unroll
                for (int jj = 0; jj < 2; ++jj) {
                    size_t off = ((size_t)n * CCH + kh * 32 + 2 * cgrp + cc) * TOT_S
                               + sb + 2 * sp + 32 * (2 * half + jj);
                    off = off > XLIM ? XLIM : off;
                    ax[kh][cc][jj] = *(const float2*)(x + off);
                    ap[kh][cc][jj] = *(const float2*)(pos + off);
                }

        f32x4 acc[4][2] = {};
        for (int k0 = 0; k0 < CCH; k0 += 64) {
            *(u16x8*)wdst = w0; *(u16x8*)(wdst + 8) = w1;
#pragma unroll
            for (int kh = 0; kh < 2; ++kh)
#pragma unroll
                for (int jj = 0; jj < 2; ++jj)
#pragma unroll
                    for (int i = 0; i < 2; ++i) {
                        const int s = 2 * sp + 32 * (2 * half + jj) + i;
                        const float lo = (i ? ax[kh][0][jj].y + ap[kh][0][jj].y
                                            : ax[kh][0][jj].x + ap[kh][0][jj].x)
                                         * mkm[jj * 2 + i];
                        const float hi = (i ? ax[kh][1][jj].y + ap[kh][1][jj].y
                                            : ax[kh][1][jj].x + ap[kh][1][jj].x)
                                         * mkm[jj * 2 + i];
                        *(unsigned int*)&Al[kh][(size_t)s * PITCH + 2 * cgrp] =
                            (unsigned int)f2bf(lo) | ((unsigned int)f2bf(hi) << 16);
                    }
            __syncthreads();
            if (k0 + 64 < CCH) {
                if (!wz) {
                    w0 = *(const u16x8*)(wsrc + k0 + 64);
                    w1 = *(const u16x8*)(wsrc + k0 + 72);
                }
#pragma unroll
                for (int kh = 0; kh < 2; ++kh)
#pragma unroll
                    for (int cc = 0; cc < 2; ++cc)
#pragma unroll
                        for (int jj = 0; jj < 2; ++jj) {
                            size_t off = ((size_t)n * CCH + k0 + 64 + kh * 32
                                          + 2 * cgrp + cc) * TOT_S
                                       + sb + 2 * sp + 32 * (2 * half + jj);
                            off = off > XLIM ? XLIM : off;
                            ax[kh][cc][jj] = *(const float2*)(x + off);
                            ap[kh][cc][jj] = *(const float2*)(pos + off);
                        }
            }
#pragma unroll
            for (int kh = 0; kh < 2; ++kh) {
                short8 af[4], bfr[2];
#pragma unroll
                for (int mt = 0; mt < 4; ++mt)
                    af[mt] = *(const short8*)&Wl[kh][(m0 + mt * 16 + row16) * PITCH + q * 8];
#pragma unroll
                for (int nt = 0; nt < 2; ++nt)
                    bfr[nt] = *(const short8*)&Al[kh][(n0 + nt * 16 + row16) * PITCH + q * 8];
#pragma unroll
                for (int mt = 0; mt < 4; ++mt)
#pragma unroll
                    for (int nt = 0; nt < 2; ++nt)
                        acc[mt][nt] = __builtin_amdgcn_mfma_f32_16x16x32_bf16(
                            af[mt], bfr[nt], acc[mt][nt], 0, 0, 0);
            }
            __syncthreads();
        }

#pragma unroll
        for (int nt = 0; nt < 2; ++nt) {
            const int s = sb + n0 + nt * 16 + row16;
            if (s >= TOT_S) continue;
            float* orow = offw + ((size_t)n * TOT_S + s) * 96;
#pragma unroll
            for (int mt = 0; mt < 4; ++mt) {
                const int o = m0 + mt * 16 + q * 4;
                if (o < 96) {
                    const float* bsrc = (o < 64) ? (bloc + o) : (bw + o - 64);
                    const f32x4 bb = *(const f32x4*)bsrc;
                    f32x4 v = acc[mt][nt];
                    v[0] += bb[0]; v[1] += bb[1]; v[2] += bb[2]; v[3] += bb[3];
                    *(f32x4*)(orow + o) = v;
                }
            }
        }
    }
}

// ---------------------------------------------------------------------------
// Sampling v2 (unchanged): ONE WAVE PER (n,s).
// ---------------------------------------------------------------------------
__global__ __launch_bounds__(256)
void sample_attn(const unsigned short* __restrict__ value,  // (N,S,512) bf16
                 const float* __restrict__ offw,            // (N,S,96)
                 const float* __restrict__ vsizes,
                 const float* __restrict__ vscales,
                 unsigned short* __restrict__ samp)         // (N,S,512) bf16
{
    const int lane = threadIdx.x;
    const int item = blockIdx.x * blockDim.y + threadIdx.y;
    const int total = NBATCH * TOT_S;
    if (item >= total) return;
    const int s = item % TOT_S;
    const int n = item / TOT_S;
    const int m = lane >> 3;

    int lvl; float prex, prey;
    if (s < 10000)      { lvl = 0; const int l = s;         const int qq = l / 100; prey = qq + 0.5f; prex = (l - qq * 100) + 0.5f; }
    else if (s < 12500) { lvl = 1; const int l = s - 10000; const int qq = l / 50;  prey = qq + 0.5f; prex = (l - qq * 50)  + 0.5f; }
    else if (s < 13125) { lvl = 2; const int l = s - 12500; const int qq = l / 25;  prey = qq + 0.5f; prex = (l - qq * 25)  + 0.5f; }
    else                { lvl = 3; const int l = s - 13125; const int qq = l / 13;  prey = qq + 0.5f; prex = (l - qq * 13)  + 0.5f; }

    const float* ow = offw + ((size_t)n * TOT_S + s) * 96;

    const float w0 = ow[64 + m * 4 + 0], w1 = ow[64 + m * 4 + 1];
    const float w2 = ow[64 + m * 4 + 2], w3 = ow[64 + m * 4 + 3];
    const float mx = fmaxf(fmaxf(w0, w1), fmaxf(w2, w3));
    const float e0 = expf(w0 - mx), e1 = expf(w1 - mx), e2 = expf(w2 - mx), e3 = expf(w3 - mx);
    const float inv = 1.f / (e0 + e1 + e2 + e3);
    const float wgt[4] = { e0 * inv, e1 * inv, e2 * inv, e3 * inv };

    const int HS[4]  = { 100, 50, 25, 13 };
    const int WS[4]  = { 100, 50, 25, 13 };
    const int CUR[4] = { 0, 10000, 12500, 13125 };

    const float invsx = 1.f / vsizes[((n * 4) + lvl) * 2 + 0];
    const float invsy = 1.f / vsizes[((n * 4) + lvl) * 2 + 1];
    const unsigned short* vbase = value + (size_t)n * TOT_S * CCH + lane * 8;

    float acc[8] = {};
#pragma unroll
    for (int f = 0; f < 4; ++f) {
        const float offx = ow[(m * 4 + f) * 2 + 0];
        const float offy = ow[(m * 4 + f) * 2 + 1];
        const float scx = 2.f * vscales[((n * 4) + f) * 2 + 0] * invsx;
        const float scy = 2.f * vscales[((n * 4) + f) * 2 + 1] * invsy;
        const int Wf = WS[f], Hf = HS[f], cf = CUR[f];
        const float xi = (offx + prex) * scx * (Wf * 0.5f) - 0.5f;
        const float yi = (offy + prey) * scy * (Hf * 0.5f) - 0.5f;
        const float x0f = floorf(xi), y0f = floorf(yi);
        const float wx1 = xi - x0f, wy1 = yi - y0f;
        const float wx0 = 1.f - wx1, wy0 = 1.f - wy1;
        const int x0 = (int)x0f, y0 = (int)y0f;
        const bool xin0 = (x0 >= 0) && (x0 < Wf);
        const bool xin1 = (x0 + 1 >= 0) && (x0 + 1 < Wf);
        const bool yin0 = (y0 >= 0) && (y0 < Hf);
        const bool yin1 = (y0 + 1 >= 0) && (y0 + 1 < Hf);
        const float cw00 = (xin0 && yin0) ? wgt[f] * wx0 * wy0 : 0.f;
        const float cw10 = (xin1 && yin0) ? wgt[f] * wx1 * wy0 : 0.f;
        const float cw01 = (xin0 && yin1) ? wgt[f] * wx0 * wy1 : 0.f;
        const float cw11 = (xin1 && yin1) ? wgt[f] * wx1 * wy1 : 0.f;
        const int x0c = min(max(x0, 0), Wf - 1);
        const int x1c = min(max(x0 + 1, 0), Wf - 1);
        const int y0c = min(max(y0, 0), Hf - 1);
        const int y1c = min(max(y0 + 1, 0), Hf - 1);
        const unsigned short* row0 = vbase + (size_t)(cf + y0c * Wf) * CCH;
        const unsigned short* row1 = vbase + (size_t)(cf + y1c * Wf) * CCH;
        const u16x8 v00 = *(const u16x8*)(row0 + (size_t)x0c * CCH);
        const u16x8 v10 = *(const u16x8*)(row0 + (size_t)x1c * CCH);
        const u16x8 v01 = *(const u16x8*)(row1 + (size_t)x0c * CCH);
        const u16x8 v11 = *(const u16x8*)(row1 + (size_t)x1c * CCH);
#pragma unroll
        for (int j = 0; j < 8; ++j) {
            acc[j] += cw00 * bf2f(v00[j]) + cw10 * bf2f(v10[j])
                    + cw01 * bf2f(v01[j]) + cw11 * bf2f(v11[j]);
        }
    }

    u16x8 ov;
#pragma unroll
    for (int j = 0; j < 8; ++j) ov[j] = f2bf(acc[j]);
    *(u16x8*)(samp + ((size_t)n * TOT_S + s) * CCH + lane * 8) = ov;
}

// ---------------------------------------------------------------------------
// MFMA GEMM 3 v6: global_load_lds staging (width 16) for BOTH operands,
// double-buffered, BK=64, one barrier/iter. LDS linear [kh][128][32] (64B
// rows) with involutive q-swizzle q' = q ^ ((row>>1)&3) applied to the
// pre-swizzled GLOBAL source and the fragment reads (LDS itself stays
// linear, as global_load_lds requires). 8-way -> 2-way bank access.
// ---------------------------------------------------------------------------
__global__ __launch_bounds__(512)
void gemm_out_mfma(const unsigned short* __restrict__ Wob,
                   const unsigned short* __restrict__ Sampb,
                   const float* __restrict__ bo, const float* __restrict__ scale,
                   float* __restrict__ out)
{
    __shared__ unsigned short Sl[2][2][128 * 32];   // [buf][kh] 8KB each
    __shared__ unsigned short Wl[2][2][128 * 32];
    const int n  = blockIdx.z;
    const int ob = blockIdx.y * 128;
    const int sb = blockIdx.x * 128;
    const int tid = threadIdx.x;
    const int wave = tid >> 6, lane = tid & 63;
    const int m0 = (wave & 1) * 64, n0 = (wave >> 1) * 32;
    const int row16 = lane & 15, q = lane >> 4;

    // staging: wave w fills rows [16w,16w+16) of each (op,kh); lane's 16B
    // lands at ldsbase + lane*16 (HW rule). row = 16w + (lane>>2),
    // swizzled col-granule q_st = (lane&3) ^ ((row>>1)&3).
    const int row_st = wave * 16 + (lane >> 2);
    const int q_st   = (lane & 3) ^ ((row_st >> 1) & 3);
    const int s_g    = min(sb + row_st, TOT_S - 1);
    const unsigned short* sgbase =
        Sampb + ((size_t)n * TOT_S + s_g) * CCH + q_st * 8;
    const unsigned short* wgbase =
        Wob + ((size_t)(ob + row_st)) * CCH + q_st * 8;
    const int ldsoff = wave * 512;   // 16 rows * 32 elems

    // fragment read swizzle: key depends only on row16 (tile rows are
    // multiples of 16, so (row>>1)&3 == (row16>>1)&3)
    const int qx = (q ^ ((row16 >> 1) & 3)) * 8;

#define GL16(gp, lp)                                                          \
    __builtin_amdgcn_global_load_lds((glb_u32*)(gp), (lds_u32*)(lp), 16, 0, 0)

    // prologue: stage tile 0 into buf 0
#pragma unroll
    for (int kh = 0; kh < 2; ++kh) {
        GL16(sgbase + kh * 32, &Sl[0][kh][ldsoff]);
        GL16(wgbase + kh * 32, &Wl[0][kh][ldsoff]);
    }
    __syncthreads();

    f32x4 acc[4][2] = {};
    int cur = 0;
    for (int k0 = 0; k0 < CCH; k0 += 64) {
        if (k0 + 64 < CCH) {
#pragma unroll
            for (int kh = 0; kh < 2; ++kh) {
                GL16(sgbase + k0 + 64 + kh * 32, &Sl[cur ^ 1][kh][ldsoff]);
                GL16(wgbase + k0 + 64 + kh * 32, &Wl[cur ^ 1][kh][ldsoff]);
            }
        }
#pragma unroll
        for (int kh = 0; kh < 2; ++kh) {
            short8 af[4], bfr[2];
#pragma unroll
            for (int mt = 0; mt < 4; ++mt)
                af[mt] = *(const short8*)&Sl[cur][kh][(m0 + mt * 16 + row16) * 32 + qx];
#pragma unroll
            for (int nt = 0; nt < 2; ++nt)
                bfr[nt] = *(const short8*)&Wl[cur][kh][(n0 + nt * 16 + row16) * 32 + qx];
#pragma unroll
            for (int mt = 0; mt < 4; ++mt)
#pragma unroll
                for (int nt = 0; nt < 2; ++nt)
                    acc[mt][nt] = __builtin_amdgcn_mfma_f32_16x16x32_bf16(
                        af[mt], bfr[nt], acc[mt][nt], 0, 0, 0);
        }
        __syncthreads();   // drains outstanding global_load_lds (vmcnt)
        cur ^= 1;
    }
#undef GL16

#pragma unroll
    for (int nt = 0; nt < 2; ++nt) {
        const int o = ob + n0 + nt * 16 + row16;
        const float bo_ = bo[o];
        const float sc_ = scale[o];
        float* orow = out + ((size_t)n * CCH + o) * (size_t)TOT_S;
#pragma unroll
        for (int mt = 0; mt < 4; ++mt) {
            const int s0 = sb + m0 + mt * 16 + q * 4;
            const f32x4 a = acc[mt][nt];
            if (s0 + 3 < TOT_S) {
                float2 v0 = make_float2((a[0] + bo_) * sc_, (a[1] + bo_) * sc_);
                float2 v1 = make_float2((a[2] + bo_) * sc_, (a[3] + bo_) * sc_);
                *(float2*)(orow + s0) = v0;
                *(float2*)(orow + s0 + 2) = v1;
            } else {
                for (int i = 0; i < 4; ++i)
                    if (s0 + i < TOT_S) orow[s0 + i] = (a[i] + bo_) * sc_;
            }
        }
    }
}

// ---------------------------------------------------------------------------
extern "C" void kernel_launch(void* const* d_in, const int* in_sizes, int n_in,
                              void* d_out, int out_size, void* d_ws, size_t ws_size,
                              hipStream_t stream)
{
    const float* x     = (const float*)d_in[0];
    const float* pos   = (const float*)d_in[1];
    const unsigned char* mask = (const unsigned char*)d_in[2];
    const float* vsz   = (const float*)d_in[3];
    const float* vsc   = (const float*)d_in[4];
    const float* Wv    = (const float*)d_in[5];
    const float* bv    = (const float*)d_in[6];
    const float* Wloc  = (const float*)d_in[7];
    const float* bloc  = (const float*)d_in[8];
    const float* Ww    = (const float*)d_in[9];
    const float* bw    = (const float*)d_in[10];
    const float* Wo    = (const float*)d_in[11];
    const float* bo    = (const float*)d_in[12];
    const float* scale = (const float*)d_in[13];
    float* out = (float*)d_out;

    const size_t SC = (size_t)TOT_S * CCH;
    unsigned short* valb  = (unsigned short*)d_ws;
    unsigned short* sampb = valb  + 2 * SC;
    float* offw = (float*)(sampb + 2 * SC);
    unsigned short* wvb = (unsigned short*)(offw + 2 * (size_t)TOT_S * 96);
    unsigned short* wob = wvb + 512 * 512;
    unsigned short* wlb = wob + 512 * 512;
    unsigned short* wwb = wlb + 64 * 512;

    cast_all_f32_bf16<<<560, 256, 0, stream>>>(Wv, Wo, Wloc, Ww,
                                               wvb, wob, wlb, wwb);

    const int sTiles = (TOT_S + 127) / 128;  // 104

    gemm_val_offw_mfma<<<dim3(sTiles, 5, NBATCH), 512, 0, stream>>>(
        wvb, wlb, wwb, bv, bloc, bw, x, pos, mask, valb, offw);

    const int items = NBATCH * TOT_S;   // one wave per (n,s)
    sample_attn<<<(items + 3) / 4, dim3(64, 4), 0, stream>>>(valb, offw, vsz, vsc, sampb);

    gemm_out_mfma<<<dim3(sTiles, CCH / 128, NBATCH), 512, 0, stream>>>(
        wob, sampb, bo, scale, out);
}